// Round 5
// baseline (613.749 us; speedup 1.0000x reference)
//
#include <hip/hip_runtime.h>
#include <stdint.h>

typedef unsigned short u16;
typedef __attribute__((ext_vector_type(8))) short short8;
typedef __attribute__((ext_vector_type(4))) float f32x4;
typedef __attribute__((ext_vector_type(4))) int i32x4;

#define EPSF 1e-5f
#define LGKM0 asm volatile("s_waitcnt lgkmcnt(0)" ::: "memory")
#define VM0   asm volatile("s_waitcnt vmcnt(0)" ::: "memory")
#define BAR   __builtin_amdgcn_s_barrier()

__device__ __forceinline__ u16 f2bf(float f) {
  uint32_t u = __float_as_uint(f);
  u += 0x7FFFu + ((u >> 16) & 1u);
  return (u16)(u >> 16);
}
__device__ __forceinline__ u16 sgnbf(float y) {
  return y > 0.f ? (u16)0x3F80 : (y < 0.f ? (u16)0xBF80 : (u16)0);
}

// B-pack layout: element (step, o, k) lives at
//   ((step*4 + (o>>6))*64 + ((k>>3)&3)*16 + (o&15))*64 + ((k>>5)*4 + ((o>>4)&3))*8 + (k&7)
// so lane (kq,li) of wave wn reads its full K=64 fragment as 128 contiguous bytes.
__device__ __forceinline__ size_t belem(int st, int o, int k) {
  return ((size_t)((st * 4 + (o >> 6)) * 64 + ((k >> 3) & 3) * 16 + (o & 15))) * 64 +
         (((k >> 5) * 4 + ((o >> 4) & 3)) << 3) + (k & 7);
}

// ---------------- BN1 stats (x is NCHW f32: 32,128,64,64) ----------------
__global__ void bn1_stage1(const float* __restrict__ x, float* __restrict__ p1) {
  int c = blockIdx.x >> 2, s = blockIdx.x & 3;
  int tid = threadIdx.x;
  float sum = 0.f, sq = 0.f;
  for (int n = s * 8; n < s * 8 + 8; ++n) {
    const f32x4* bp = (const f32x4*)(x + (((size_t)(n * 128 + c)) << 12));
    #pragma unroll 4
    for (int i = tid; i < 1024; i += 256) {
      f32x4 v = bp[i];
      sum += v[0] + v[1] + v[2] + v[3];
      sq  += v[0]*v[0] + v[1]*v[1] + v[2]*v[2] + v[3]*v[3];
    }
  }
  __shared__ float rs[256], rq[256];
  rs[tid] = sum; rq[tid] = sq; __syncthreads();
  for (int st = 128; st > 0; st >>= 1) {
    if (tid < st) { rs[tid] += rs[tid + st]; rq[tid] += rq[tid + st]; }
    __syncthreads();
  }
  if (tid == 0) { p1[blockIdx.x] = rs[0]; p1[512 + blockIdx.x] = rq[0]; }
}

__global__ void bn1_stage2(const float* __restrict__ p1, const float* __restrict__ g,
                           const float* __restrict__ b, float* __restrict__ sc,
                           float* __restrict__ off) {
  int c = threadIdx.x; // 128 threads
  float s = 0.f, q = 0.f;
  for (int k = 0; k < 4; ++k) { s += p1[c * 4 + k]; q += p1[512 + c * 4 + k]; }
  float mean = s * (1.f / 131072.f);
  float var  = q * (1.f / 131072.f) - mean * mean;
  float is = rsqrtf(var + EPSF);
  float scv = g[c] * is;
  sc[c] = scv;
  off[c] = b[c] - mean * scv;
}

// ---------------- BN2 stage2: reduce 2048 per-block partials ----------------
__global__ void bn2_stage2b(const float* __restrict__ pS, const float* __restrict__ pQ,
                            const float* __restrict__ g, const float* __restrict__ bb,
                            float* __restrict__ sc, float* __restrict__ off) {
  int o = blockIdx.x, t = threadIdx.x;
  __shared__ float rs[256], rq[256];
  const float* ps = pS + (size_t)o * 2048;
  const float* pq = pQ + (size_t)o * 2048;
  float s = 0.f, q = 0.f;
  #pragma unroll
  for (int k = 0; k < 8; ++k) { s += ps[t + k * 256]; q += pq[t + k * 256]; }
  rs[t] = s; rq[t] = q; __syncthreads();
  for (int st = 128; st > 0; st >>= 1) {
    if (t < st) { rs[t] += rs[t + st]; rq[t] += rq[t + st]; }
    __syncthreads();
  }
  if (t == 0) {
    float mean = rs[0] * (1.f / 131072.f);
    float var  = rq[0] * (1.f / 131072.f) - mean * mean;
    float is = rsqrtf(var + EPSF);
    float scv = g[o] * is;
    sc[o] = scv;
    off[o] = bb[o] - mean * scv;
  }
}

// ---------------- weight prep (B-pack layout) ----------------
__device__ __forceinline__ float blk_reduce(float v, float* red) {
  int t = threadIdx.x;
  red[t] = v; __syncthreads();
  for (int st = 128; st > 0; st >>= 1) {
    if (t < st) red[t] += red[t + st];
    __syncthreads();
  }
  float r = red[0]; __syncthreads();
  return r;
}

__global__ void prep_weights(const float* __restrict__ w1, const float* __restrict__ w2,
                             const float* __restrict__ wsk, u16* __restrict__ w1B,
                             u16* __restrict__ w2B, float* __restrict__ alpha1,
                             float* __restrict__ alpha2) {
  int o = blockIdx.x, t = threadIdx.x;
  __shared__ float red[256];
  float s = 0.f;
  for (int j = t; j < 1152; j += 256) s += fabsf(w1[(size_t)o * 1152 + j]);
  float a1 = blk_reduce(s, red) * (1.f / 1152.f);
  if (t == 0) alpha1[o] = a1;
  for (int j = t; j < 1152; j += 256) {
    int st = j >> 6, k = j & 63;
    int cc = st / 9, tap = st % 9;
    int c = cc * 64 + k;
    float w = w1[(size_t)o * 1152 + c * 9 + tap];
    w1B[belem(st, o, k)] = sgnbf(w);
  }
  s = 0.f;
  for (int j = t; j < 2304; j += 256) s += fabsf(w2[(size_t)o * 2304 + j]);
  float a2 = blk_reduce(s, red) * (1.f / 2304.f);
  if (t == 0) alpha2[o] = a2;
  for (int j = t; j < 2304; j += 256) {
    int st = j >> 6, k = j & 63;
    int cc = st / 9, tap = st % 9;
    int c = cc * 64 + k;
    float w = w2[(size_t)o * 2304 + c * 9 + tap];
    w2B[belem(st, o, k)] = sgnbf(w);
  }
  s = 0.f;
  for (int j = t; j < 128; j += 256) s += fabsf(wsk[o * 128 + j]);
  float ask = blk_reduce(s, red) * (1.f / 128.f);
  float ratio = ask / a2;
  for (int j = t; j < 128; j += 256) {
    int st = 36 + (j >> 6), k = j & 63;
    float w = wsk[o * 128 + j];
    float v = w > 0.f ? ratio : (w < 0.f ? -ratio : 0.f);
    w2B[belem(st, o, k)] = f2bf(v);
  }
}

// ---------------- temb = t @ tw^T + tb ----------------
__global__ void temb_k(const float* __restrict__ t, const float* __restrict__ tw,
                       const float* __restrict__ tb, float* __restrict__ temb) {
  int bb = blockIdx.x, o = threadIdx.x;
  __shared__ float tl[512];
  tl[o] = t[bb * 512 + o];
  tl[o + 256] = t[bb * 512 + 256 + o];
  __syncthreads();
  float acc = tb[o];
  #pragma unroll 8
  for (int k = 0; k < 512; ++k) acc += tl[k] * tw[(size_t)o * 512 + k];
  temb[bb * 256 + o] = acc;
}

// ---------------- border zero: 128 planes of [66][66][64], borders only ----------------
__global__ void border_zero(u16* __restrict__ Apad) {
  u16* plane = Apad + (size_t)blockIdx.x * 66 * 66 * 64;
  int tid = threadIdx.x;
  i32x4 z = {};
  for (int idx = tid; idx < 260; idx += 256) {
    int row, px;
    if (idx < 66) { row = 0; px = idx; }
    else if (idx < 132) { row = 65; px = idx - 66; }
    else { int e = idx - 132; row = 1 + (e >> 1); px = (e & 1) * 65; }
    u16* p = plane + (row * 66 + px) * 64;
    #pragma unroll
    for (int i = 0; i < 8; ++i) *(i32x4*)(p + i * 8) = z;
  }
}

// -------- binact1: x NCHW -> a1p planes [b][cc=2][66][66][64] + xb [m][128] --------
__global__ void binact1(const float* __restrict__ x, const float* __restrict__ sc,
                        const float* __restrict__ off, u16* __restrict__ a1p,
                        u16* __restrict__ xb) {
  int b = blockIdx.x >> 6, y = blockIdx.x & 63, tid = threadIdx.x;
  __shared__ u16 ls[64 * 136];
  __shared__ u16 lx[64 * 136];
  int c = tid >> 1, x0 = (tid & 1) * 32;
  const float* src = x + (((size_t)(b * 128 + c)) << 12) + y * 64 + x0;
  float s0 = sc[c], o0 = off[c];
  #pragma unroll
  for (int i = 0; i < 32; i += 4) {
    f32x4 v = *(const f32x4*)(src + i);
    #pragma unroll
    for (int j = 0; j < 4; ++j) {
      int xc = x0 + i + j;
      float yv = s0 * v[j] + o0;
      ls[xc * 136 + c] = sgnbf(yv);
      lx[xc * 136 + c] = f2bf(v[j]);
    }
  }
  __syncthreads();
  int xx = tid >> 2, cg = (tid & 3) * 32;
  int cc = cg >> 6, ch0 = cg & 63;
  u16* pdst = a1p + (((size_t)(b * 2 + cc) * 66 + y + 1) * 66 + xx + 1) * 64 + ch0;
  u16* xdst = xb + ((size_t)blockIdx.x * 64 + xx) * 128 + cg;
  #pragma unroll
  for (int i = 0; i < 32; i += 8) {
    *(i32x4*)(pdst + i) = *(const i32x4*)&ls[xx * 136 + cg + i];
    *(i32x4*)(xdst + i) = *(const i32x4*)&lx[xx * 136 + cg + i];
  }
}

// -------- binact2: h [m][256] f32 -> a2p planes [b][cc=4][66][66][64] --------
__global__ void binact2(const float* __restrict__ h, const float* __restrict__ sc,
                        const float* __restrict__ off, u16* __restrict__ a2p) {
  int b = blockIdx.x >> 6, y = blockIdx.x & 63, tid = threadIdx.x;
  __shared__ float s_sc[256], s_off[256];
  s_sc[tid] = sc[tid]; s_off[tid] = off[tid];
  __syncthreads();
  const f32x4* src = (const f32x4*)(h + (size_t)blockIdx.x * 16384);
  #pragma unroll 4
  for (int i = tid; i < 4096; i += 256) {
    f32x4 v = src[i];
    int e = i * 4;
    int xx = e >> 8, c0 = e & 255;
    int cc = c0 >> 6, ch = c0 & 63;
    u16 r0 = sgnbf(s_sc[c0 + 0] * v[0] + s_off[c0 + 0]);
    u16 r1 = sgnbf(s_sc[c0 + 1] * v[1] + s_off[c0 + 1]);
    u16 r2 = sgnbf(s_sc[c0 + 2] * v[2] + s_off[c0 + 2]);
    u16 r3 = sgnbf(s_sc[c0 + 3] * v[3] + s_off[c0 + 3]);
    uint32_t lo = (uint32_t)r0 | ((uint32_t)r1 << 16);
    uint32_t hi = (uint32_t)r2 | ((uint32_t)r3 << 16);
    uint2 pack; pack.x = lo; pack.y = hi;
    u16* dst = a2p + (((size_t)(b * 4 + cc) * 66 + y + 1) * 66 + xx + 1) * 64 + ch;
    *(uint2*)dst = pack;
  }
}

// ---------------- conv: B-in-registers, barrier-free taps ----------------
// M-tile = 64 (one image row), N = 256, 256 threads = 4 waves (1M x 4N).
// A: double-buffered halo window [3][66][64] (XOR-swizzled via pre-swizzled
//    source + linear global_load_lds dest), prefetched at chunk START ->
//    ONE barrier per 9-tap chunk.
// B: per-lane 128B contiguous fragments loaded global->reg, prefetched one
//    step ahead (L1-resident, 32KB/step shared per CU). No B in LDS.
template <int CPS, int NEXTRA, bool ADD_TEMB, bool STATS, bool DIRECT>
__global__ __launch_bounds__(256, 2) void convk(
    const u16* __restrict__ Apad, const u16* __restrict__ Xtra,
    const u16* __restrict__ wB, const float* __restrict__ alpha,
    const float* __restrict__ temb, float* __restrict__ outp,
    float* __restrict__ pS, float* __restrict__ pQ) {
  constexpr int NSTEP = 9 * CPS + NEXTRA;
  constexpr int NCH = CPS + NEXTRA;
  __shared__ u16 lA[2][3 * 66 * 64];   // 2 x 25344 B
  const int tid = threadIdx.x;
  const int lane = tid & 63, wn = tid >> 6;
  const int kq = lane >> 4, li = lane & 15;

  const int bid = blockIdx.x;
  const int tile = (bid & 7) * 256 + (bid >> 3);   // XCD-chunked swizzle (2048%8==0)
  const int m0 = tile * 64;
  const int b = tile >> 6, y = tile & 63;

  struct Bfrag { short8 v[8]; };
  auto loadB = [&](int s, Bfrag& f) {
    const short8* p = (const short8*)(wB + (size_t)s * 16384 + ((wn * 64 + lane) << 6));
    #pragma unroll
    for (int j = 0; j < 8; ++j) f.v[j] = p[j];
  };

  // A window chunk load: 1584 granules of 16B, linear LDS dest, swizzled source
  auto winLoad = [&](int c, int buf) {
    const u16* gp = Apad + ((size_t)(b * CPS + c) * 66 + y) * 4224;
    #pragma unroll
    for (int k = 0; k < 6; ++k) {
      int g = tid + k * 256;
      int row = g / 528, rem = g - row * 528;
      int px = rem >> 3, c16 = rem & 7;
      const u16* src = gp + (row * 66 + px) * 64 + ((c16 ^ (px & 7)) << 3);
      u16* dst = lA[buf] + (size_t)(k * 256 + (tid & ~63)) * 8;
      __builtin_amdgcn_global_load_lds(
          (const __attribute__((address_space(1))) void*)src,
          (__attribute__((address_space(3))) void*)dst, 16, 0, 0);
    }
    if (tid < 48) {
      int g = 1536 + tid;
      int rem = g - 1056;           // row 2
      int px = rem >> 3, c16 = rem & 7;
      const u16* src = gp + (2 * 66 + px) * 64 + ((c16 ^ (px & 7)) << 3);
      u16* dst = lA[buf] + (size_t)1536 * 8;
      __builtin_amdgcn_global_load_lds(
          (const __attribute__((address_space(1))) void*)src,
          (__attribute__((address_space(3))) void*)dst, 16, 0, 0);
    }
  };
  // extra chunk (skip input): 512 granules -> row0, px 1..64
  auto extLoad = [&](int e, int buf) {
    #pragma unroll
    for (int k = 0; k < 2; ++k) {
      int i = tid + k * 256;
      int ml = i >> 3, c16 = i & 7;
      const u16* src = Xtra + (size_t)(m0 + ml) * 128 + (e << 6) +
                       ((c16 ^ ((ml + 1) & 7)) << 3);
      u16* dst = lA[buf] + (size_t)(8 + k * 256 + (tid & ~63)) * 8;
      __builtin_amdgcn_global_load_lds(
          (const __attribute__((address_space(1))) void*)src,
          (__attribute__((address_space(3))) void*)dst, 16, 0, 0);
    }
  };

  // swizzled A-fragment base pointers (buf/dy/f become immediate offsets)
  const u16* pA[3][2];
  #pragma unroll
  for (int dx = 0; dx < 3; ++dx)
    #pragma unroll
    for (int ks = 0; ks < 2; ++ks)
      pA[dx][ks] = &lA[0][(li + dx) * 64 + ((ks * 32 + kq * 8) ^ (((li + dx) & 7) << 3))];

  f32x4 acc[4][4] = {};
  Bfrag Bc, Bn;

  auto compute = [&](int dy, int dx, int buf, const Bfrag& B) {
    short8 af[2][4];
    #pragma unroll
    for (int ks = 0; ks < 2; ++ks)
      #pragma unroll
      for (int f = 0; f < 4; ++f)
        af[ks][f] = *(const short8*)(pA[dx][ks] + buf * 12672 + dy * 4224 + f * 1024);
    __builtin_amdgcn_s_setprio(1);
    #pragma unroll
    for (int ks = 0; ks < 2; ++ks)
      #pragma unroll
      for (int mf = 0; mf < 4; ++mf)
        #pragma unroll
        for (int nf = 0; nf < 4; ++nf)
          acc[mf][nf] = __builtin_amdgcn_mfma_f32_16x16x32_bf16(
              af[ks][mf], B.v[ks * 4 + nf], acc[mf][nf], 0, 0, 0);
    __builtin_amdgcn_s_setprio(0);
  };

  // prologue
  winLoad(0, 0);
  loadB(0, Bc);
  VM0; BAR;

  #pragma unroll
  for (int s = 0; s < NSTEP; ++s) {
    const int c  = (s < 9 * CPS) ? s / 9 : CPS + (s - 9 * CPS);
    const int t  = (s < 9 * CPS) ? s % 9 : 0;
    const int dy = (s < 9 * CPS) ? t / 3 : 0;
    const int dx = (s < 9 * CPS) ? t % 3 : 1;
    const bool chunkStart = (s >= 9 * CPS) || (t == 0);
    const bool chunkEnd   = (s >= 9 * CPS) || (t == 8);

    if (s + 1 < NSTEP) loadB(s + 1, Bn);
    if (chunkStart && (c + 1) < NCH) {
      if (c + 1 < CPS) winLoad(c + 1, (c + 1) & 1);
      else extLoad(c + 1 - CPS, (c + 1) & 1);
    }
    compute(dy, dx, c & 1, Bc);
    Bc = Bn;
    if (chunkEnd && (s + 1) < NSTEP) { LGKM0; VM0; BAR; }
  }

  const int cb = wn * 64 + li;

  if constexpr (STATS) {
    // write h + deterministic per-block BN2 partials (no LDS needed)
    float ps[4] = {0.f, 0.f, 0.f, 0.f}, pq[4] = {0.f, 0.f, 0.f, 0.f};
    #pragma unroll
    for (int nf = 0; nf < 4; ++nf) {
      int o = cb + nf * 16;
      float al = alpha[o];
      float ta = ADD_TEMB ? temb[b * 256 + o] : 0.f;
      #pragma unroll
      for (int mf = 0; mf < 4; ++mf) {
        #pragma unroll
        for (int r = 0; r < 4; ++r) {
          int m = m0 + mf * 16 + 4 * kq + r;
          float v = acc[mf][nf][r] * al + ta;
          outp[(size_t)m * 256 + o] = v;
          ps[nf] += v; pq[nf] += v * v;
        }
      }
    }
    #pragma unroll
    for (int nf = 0; nf < 4; ++nf) {
      ps[nf] += __shfl_xor(ps[nf], 16); ps[nf] += __shfl_xor(ps[nf], 32);
      pq[nf] += __shfl_xor(pq[nf], 16); pq[nf] += __shfl_xor(pq[nf], 32);
    }
    if (lane < 16) {
      #pragma unroll
      for (int nf = 0; nf < 4; ++nf) {
        int o = wn * 64 + nf * 16 + lane;
        pS[(size_t)o * 2048 + bid] = ps[nf];
        pQ[(size_t)o * 2048 + bid] = pq[nf];
      }
    }
  } else if constexpr (DIRECT) {
    // NCHW transpose epilogue via LDS quarter-tiles [64 x][65]
    float* tb2 = (float*)lA[0];
    const int o_t = tid >> 2, xc = tid & 3;
    float* obase = outp + (((size_t)b << 20)) + (y << 6);
    __syncthreads();
    #pragma unroll 1
    for (int c4 = 0; c4 < 4; ++c4) {
      if (wn == c4) {
        #pragma unroll
        for (int nf = 0; nf < 4; ++nf) {
          float al = alpha[c4 * 64 + nf * 16 + li];
          #pragma unroll
          for (int mf = 0; mf < 4; ++mf) {
            #pragma unroll
            for (int r = 0; r < 4; ++r)
              tb2[(mf * 16 + 4 * kq + r) * 65 + nf * 16 + li] = acc[mf][nf][r] * al;
          }
        }
      }
      __syncthreads();
      float* dst = obase + (((size_t)(c4 * 64 + o_t)) << 12) + (xc << 4);
      #pragma unroll
      for (int q4 = 0; q4 < 4; ++q4) {
        f32x4 v;
        #pragma unroll
        for (int e = 0; e < 4; ++e) v[e] = tb2[(xc * 16 + q4 * 4 + e) * 65 + o_t];
        *(f32x4*)(dst + q4 * 4) = v;
      }
      __syncthreads();
    }
  }
}

extern "C" void kernel_launch(void* const* d_in, const int* in_sizes, int n_in,
                              void* d_out, int out_size, void* d_ws, size_t ws_size,
                              hipStream_t stream) {
  const float* x      = (const float*)d_in[0];
  const float* t      = (const float*)d_in[1];
  const float* w1     = (const float*)d_in[2];
  const float* w2     = (const float*)d_in[3];
  const float* wskip  = (const float*)d_in[4];
  const float* gamma1 = (const float*)d_in[5];
  const float* beta1  = (const float*)d_in[6];
  const float* gamma2 = (const float*)d_in[7];
  const float* beta2  = (const float*)d_in[8];
  const float* tw     = (const float*)d_in[9];
  const float* tb     = (const float*)d_in[10];
  float* out = (float*)d_out;

  uint8_t* base = (uint8_t*)d_ws;
  size_t off = 0;
  auto alloc = [&](size_t bytes) {
    void* p = base + off;
    off += (bytes + 255) & ~(size_t)255;
    return p;
  };
  const size_t szApad = (size_t)32 * 4 * 66 * 66 * 64 * 2; // 128 planes of [66][66][64]
  u16* Apad    = (u16*)alloc(szApad);
  u16* xb      = (u16*)alloc((size_t)131072 * 128 * 2);
  float* h     = (float*)alloc((size_t)131072 * 256 * 4);
  u16* w1B     = (u16*)alloc((size_t)18 * 16384 * 2);
  u16* w2B     = (u16*)alloc((size_t)38 * 16384 * 2);
  float* temb  = (float*)alloc(32 * 256 * 4);
  float* alpha1 = (float*)alloc(256 * 4);
  float* alpha2 = (float*)alloc(256 * 4);
  float* p1    = (float*)alloc(1024 * 4);
  float* pS    = (float*)alloc((size_t)256 * 2048 * 4);
  float* pQ    = (float*)alloc((size_t)256 * 2048 * 4);
  float* sc1   = (float*)alloc(128 * 4);
  float* off1  = (float*)alloc(128 * 4);
  float* sc2   = (float*)alloc(256 * 4);
  float* off2  = (float*)alloc(256 * 4);

  // zero only the plane borders (binact1/binact2 write all interiors)
  border_zero<<<128, 256, 0, stream>>>(Apad);

  bn1_stage1<<<512, 256, 0, stream>>>(x, p1);
  bn1_stage2<<<1, 128, 0, stream>>>(p1, gamma1, beta1, sc1, off1);
  prep_weights<<<256, 256, 0, stream>>>(w1, w2, wskip, w1B, w2B, alpha1, alpha2);
  temb_k<<<32, 256, 0, stream>>>(t, tw, tb, temb);
  binact1<<<2048, 256, 0, stream>>>(x, sc1, off1, Apad, xb);

  // conv1: writes h + BN2 per-block partials
  convk<2, 0, true, true, false><<<2048, 256, 0, stream>>>(
      Apad, xb, w1B, alpha1, temb, h, pS, pQ);

  bn2_stage2b<<<256, 256, 0, stream>>>(pS, pQ, gamma2, beta2, sc2, off2);
  binact2<<<2048, 256, 0, stream>>>(h, sc2, off2, Apad);

  // conv2: direct NCHW output (skip folded into K-tail)
  convk<4, 2, false, false, true><<<2048, 256, 0, stream>>>(
      Apad, xb, w2B, alpha2, (const float*)nullptr, out,
      (float*)nullptr, (float*)nullptr);

  (void)in_sizes; (void)n_in; (void)out_size; (void)ws_size;
}

// Round 6
// 436.651 us; speedup vs baseline: 1.4056x; 1.4056x over previous
//
#include <hip/hip_runtime.h>
#include <stdint.h>

typedef unsigned short u16;
typedef __attribute__((ext_vector_type(8))) short short8;
typedef __attribute__((ext_vector_type(4))) float f32x4;
typedef __attribute__((ext_vector_type(4))) int i32x4;

#define EPSF 1e-5f
#define LGKM0 asm volatile("s_waitcnt lgkmcnt(0)" ::: "memory")
#define VM0   asm volatile("s_waitcnt vmcnt(0)" ::: "memory")
#define VM2   asm volatile("s_waitcnt vmcnt(2)" ::: "memory")
#define BAR   __builtin_amdgcn_s_barrier()

__device__ __forceinline__ u16 f2bf(float f) {
  uint32_t u = __float_as_uint(f);
  u += 0x7FFFu + ((u >> 16) & 1u);
  return (u16)(u >> 16);
}
__device__ __forceinline__ u16 sgnbf(float y) {
  return y > 0.f ? (u16)0x3F80 : (y < 0.f ? (u16)0xBF80 : (u16)0);
}

// ---------------- BN1 stats (x is NCHW f32: 32,128,64,64) ----------------
__global__ void bn1_stage1(const float* __restrict__ x, float* __restrict__ p1) {
  int c = blockIdx.x >> 2, s = blockIdx.x & 3;
  int tid = threadIdx.x;
  float sum = 0.f, sq = 0.f;
  for (int n = s * 8; n < s * 8 + 8; ++n) {
    const f32x4* bp = (const f32x4*)(x + (((size_t)(n * 128 + c)) << 12));
    #pragma unroll 4
    for (int i = tid; i < 1024; i += 256) {
      f32x4 v = bp[i];
      sum += v[0] + v[1] + v[2] + v[3];
      sq  += v[0]*v[0] + v[1]*v[1] + v[2]*v[2] + v[3]*v[3];
    }
  }
  __shared__ float rs[256], rq[256];
  rs[tid] = sum; rq[tid] = sq; __syncthreads();
  for (int st = 128; st > 0; st >>= 1) {
    if (tid < st) { rs[tid] += rs[tid + st]; rq[tid] += rq[tid + st]; }
    __syncthreads();
  }
  if (tid == 0) { p1[blockIdx.x] = rs[0]; p1[512 + blockIdx.x] = rq[0]; }
}

__global__ void bn1_stage2(const float* __restrict__ p1, const float* __restrict__ g,
                           const float* __restrict__ b, float* __restrict__ sc,
                           float* __restrict__ off) {
  int c = threadIdx.x; // 128 threads
  float s = 0.f, q = 0.f;
  for (int k = 0; k < 4; ++k) { s += p1[c * 4 + k]; q += p1[512 + c * 4 + k]; }
  float mean = s * (1.f / 131072.f);
  float var  = q * (1.f / 131072.f) - mean * mean;
  float is = rsqrtf(var + EPSF);
  float scv = g[c] * is;
  sc[c] = scv;
  off[c] = b[c] - mean * scv;
}

// ---------------- BN2 stage2: reduce per-block partials from conv1 epilogue ----------------
__global__ void bn2_stage2b(const float* __restrict__ pS, const float* __restrict__ pQ,
                            const float* __restrict__ g, const float* __restrict__ bb,
                            float* __restrict__ sc, float* __restrict__ off) {
  int o = blockIdx.x, t = threadIdx.x;
  __shared__ float rs[256], rq[256];
  const float* ps = pS + (size_t)o * 1024;
  const float* pq = pQ + (size_t)o * 1024;
  float s = ps[t] + ps[t + 256] + ps[t + 512] + ps[t + 768];
  float q = pq[t] + pq[t + 256] + pq[t + 512] + pq[t + 768];
  rs[t] = s; rq[t] = q; __syncthreads();
  for (int st = 128; st > 0; st >>= 1) {
    if (t < st) { rs[t] += rs[t + st]; rq[t] += rq[t + st]; }
    __syncthreads();
  }
  if (t == 0) {
    float mean = rs[0] * (1.f / 131072.f);
    float var  = rq[0] * (1.f / 131072.f) - mean * mean;
    float is = rsqrtf(var + EPSF);
    float scv = g[o] * is;
    sc[o] = scv;
    off[o] = bb[o] - mean * scv;
  }
}

// ---------------- weight prep ----------------
__device__ __forceinline__ float blk_reduce(float v, float* red) {
  int t = threadIdx.x;
  red[t] = v; __syncthreads();
  for (int st = 128; st > 0; st >>= 1) {
    if (t < st) red[t] += red[t + st];
    __syncthreads();
  }
  float r = red[0]; __syncthreads();
  return r;
}

// Half-tap step blocks: wS[st][o][32] u16, element (o,k) at o*32 + (k ^ ((o&3)<<3)).
// st = cc*18 + tap*2 + h covers channels cc*64 + h*32 + k of tap.
// conv1: 36 steps. conv2: 72 + 4 skip steps (st=72..75: ch = (st-72)*32 + k).
__global__ void prep_weights(const float* __restrict__ w1, const float* __restrict__ w2,
                             const float* __restrict__ wsk, u16* __restrict__ w1s,
                             u16* __restrict__ w2s, float* __restrict__ alpha1,
                             float* __restrict__ alpha2) {
  int o = blockIdx.x, t = threadIdx.x;
  __shared__ float red[256];
  float s = 0.f;
  for (int j = t; j < 1152; j += 256) s += fabsf(w1[(size_t)o * 1152 + j]);
  float a1 = blk_reduce(s, red) * (1.f / 1152.f);
  if (t == 0) alpha1[o] = a1;
  for (int j = t; j < 1152; j += 256) {
    int st = j >> 5, k = j & 31;
    int cc = st / 18, r = st % 18, tap = r >> 1, h = r & 1;
    int ch = cc * 64 + h * 32 + k;
    float w = w1[(size_t)o * 1152 + ch * 9 + tap];
    w1s[(size_t)st * 8192 + o * 32 + (k ^ ((o & 3) << 3))] = sgnbf(w);
  }
  s = 0.f;
  for (int j = t; j < 2304; j += 256) s += fabsf(w2[(size_t)o * 2304 + j]);
  float a2 = blk_reduce(s, red) * (1.f / 2304.f);
  if (t == 0) alpha2[o] = a2;
  for (int j = t; j < 2304; j += 256) {
    int st = j >> 5, k = j & 31;
    int cc = st / 18, r = st % 18, tap = r >> 1, h = r & 1;
    int ch = cc * 64 + h * 32 + k;
    float w = w2[(size_t)o * 2304 + ch * 9 + tap];
    w2s[(size_t)st * 8192 + o * 32 + (k ^ ((o & 3) << 3))] = sgnbf(w);
  }
  s = 0.f;
  for (int j = t; j < 128; j += 256) s += fabsf(wsk[o * 128 + j]);
  float ask = blk_reduce(s, red) * (1.f / 128.f);
  float ratio = ask / a2;
  for (int j = t; j < 128; j += 256) {
    int st = 72 + (j >> 5), k = j & 31;
    float w = wsk[o * 128 + j];
    float v = w > 0.f ? ratio : (w < 0.f ? -ratio : 0.f);
    w2s[(size_t)st * 8192 + o * 32 + (k ^ ((o & 3) << 3))] = f2bf(v);
  }
}

// ---------------- temb = t @ tw^T + tb ----------------
__global__ void temb_k(const float* __restrict__ t, const float* __restrict__ tw,
                       const float* __restrict__ tb, float* __restrict__ temb) {
  int bb = blockIdx.x, o = threadIdx.x;
  __shared__ float tl[512];
  tl[o] = t[bb * 512 + o];
  tl[o + 256] = t[bb * 512 + 256 + o];
  __syncthreads();
  float acc = tb[o];
  #pragma unroll 8
  for (int k = 0; k < 512; ++k) acc += tl[k] * tw[(size_t)o * 512 + k];
  temb[bb * 256 + o] = acc;
}

// ---------------- border zero: 128 planes of [66][66][64], borders only ----------------
__global__ void border_zero(u16* __restrict__ Apad) {
  u16* plane = Apad + (size_t)blockIdx.x * 66 * 66 * 64;
  int tid = threadIdx.x;
  i32x4 z = {};
  for (int idx = tid; idx < 260; idx += 256) {
    int row, px;
    if (idx < 66) { row = 0; px = idx; }
    else if (idx < 132) { row = 65; px = idx - 66; }
    else { int e = idx - 132; row = 1 + (e >> 1); px = (e & 1) * 65; }
    u16* p = plane + (row * 66 + px) * 64;
    #pragma unroll
    for (int i = 0; i < 8; ++i) *(i32x4*)(p + i * 8) = z;
  }
}

// -------- binact1: x NCHW -> a1p planes [b][cc=2][66][66][64] + xb [m][128] --------
__global__ void binact1(const float* __restrict__ x, const float* __restrict__ sc,
                        const float* __restrict__ off, u16* __restrict__ a1p,
                        u16* __restrict__ xb) {
  int b = blockIdx.x >> 6, y = blockIdx.x & 63, tid = threadIdx.x;
  __shared__ u16 ls[64 * 136];
  __shared__ u16 lx[64 * 136];
  int c = tid >> 1, x0 = (tid & 1) * 32;
  const float* src = x + (((size_t)(b * 128 + c)) << 12) + y * 64 + x0;
  float s0 = sc[c], o0 = off[c];
  #pragma unroll
  for (int i = 0; i < 32; i += 4) {
    f32x4 v = *(const f32x4*)(src + i);
    #pragma unroll
    for (int j = 0; j < 4; ++j) {
      int xc = x0 + i + j;
      float yv = s0 * v[j] + o0;
      ls[xc * 136 + c] = sgnbf(yv);
      lx[xc * 136 + c] = f2bf(v[j]);
    }
  }
  __syncthreads();
  int xx = tid >> 2, cg = (tid & 3) * 32;
  int cc = cg >> 6, ch0 = cg & 63;
  u16* pdst = a1p + (((size_t)(b * 2 + cc) * 66 + y + 1) * 66 + xx + 1) * 64 + ch0;
  u16* xdst = xb + ((size_t)blockIdx.x * 64 + xx) * 128 + cg;
  #pragma unroll
  for (int i = 0; i < 32; i += 8) {
    *(i32x4*)(pdst + i) = *(const i32x4*)&ls[xx * 136 + cg + i];
    *(i32x4*)(xdst + i) = *(const i32x4*)&lx[xx * 136 + cg + i];
  }
}

// -------- binact2: h [m][256] f32 -> a2p planes [b][cc=4][66][66][64] --------
__global__ void binact2(const float* __restrict__ h, const float* __restrict__ sc,
                        const float* __restrict__ off, u16* __restrict__ a2p) {
  int b = blockIdx.x >> 6, y = blockIdx.x & 63, tid = threadIdx.x;
  __shared__ float s_sc[256], s_off[256];
  s_sc[tid] = sc[tid]; s_off[tid] = off[tid];
  __syncthreads();
  const f32x4* src = (const f32x4*)(h + (size_t)blockIdx.x * 16384);
  #pragma unroll 4
  for (int i = tid; i < 4096; i += 256) {
    f32x4 v = src[i];
    int e = i * 4;
    int xx = e >> 8, c0 = e & 255;
    int cc = c0 >> 6, ch = c0 & 63;
    u16 r0 = sgnbf(s_sc[c0 + 0] * v[0] + s_off[c0 + 0]);
    u16 r1 = sgnbf(s_sc[c0 + 1] * v[1] + s_off[c0 + 1]);
    u16 r2 = sgnbf(s_sc[c0 + 2] * v[2] + s_off[c0 + 2]);
    u16 r3 = sgnbf(s_sc[c0 + 3] * v[3] + s_off[c0 + 3]);
    uint32_t lo = (uint32_t)r0 | ((uint32_t)r1 << 16);
    uint32_t hi = (uint32_t)r2 | ((uint32_t)r3 << 16);
    uint2 pack; pack.x = lo; pack.y = hi;
    u16* dst = a2p + (((size_t)(b * 4 + cc) * 66 + y + 1) * 66 + xx + 1) * 64 + ch;
    *(uint2*)dst = pack;
  }
}

// ---------------- window-staged implicit-GEMM conv, counted-vmcnt schedule ----------------
// M-tile = 128, N = 256, 512 threads = 8 waves (2M x 4N), 2 blocks/CU (66.5 KB LDS).
// K-step = 32 (half-tap). B double-buffered in LDS (2 x 16 KB), staged 2 steps deep
// through registers: stage(s+2)->regs, vmcnt(2), writeB(s+1) -> ONE barrier per step,
// no full vmem drain except chunk boundaries (once per 9 taps).
template <int CPS, int NEXTRA2, bool ADD_TEMB, bool STATS, bool DIRECT>
__global__ __launch_bounds__(512, 4) void convk(
    const u16* __restrict__ Apad, const u16* __restrict__ Xtra,
    const u16* __restrict__ wS, const float* __restrict__ alpha,
    const float* __restrict__ temb, float* __restrict__ outp,
    float* __restrict__ pS, float* __restrict__ pQ) {
  constexpr int NH = 18 * CPS + 2 * NEXTRA2;
  __shared__ u16 lA[4 * 66 * 64];     // 33792 B
  __shared__ u16 lB[2][256 * 32];     // 2 x 16384 B
  const int tid = threadIdx.x;
  const int lane = tid & 63, w = tid >> 6, wm = w >> 2, wn = w & 3;
  const int kq = lane >> 4, li = lane & 15;

  const int bid = blockIdx.x;
  const int tile = (bid & 7) * 128 + (bid >> 3);   // XCD-chunked swizzle
  const int m0 = tile * 128;
  const int b = m0 >> 12, row0 = (m0 >> 6) & 63;
  u16* lB0 = &lB[0][0];

  // ---- B stage: 2 granules/thread/step, pre-swizzled global -> linear LDS ----
  i32x4 rB[2][2];
  auto stageB = [&](int s, int slot) {
    const i32x4* g = (const i32x4*)(wS + (size_t)s * 8192) + tid;
    rB[slot][0] = g[0]; rB[slot][1] = g[512];
  };
  auto writeB = [&](int slot) {
    i32x4* l = (i32x4*)(lB0 + slot * 8192) + tid;
    l[0] = rB[slot][0]; l[512] = rB[slot][1];
  };

  // ---- A window: global_load_lds, linear dest + pre-swizzled per-lane source ----
  auto winLoad = [&](int c) {
    const u16* gp = Apad + ((size_t)(b * CPS + c) * 66 + row0) * 4224;
    #pragma unroll
    for (int k = 0; k < 4; ++k) {
      int p = tid + k * 512;
      int row = p / 528, offn = p - row * 528;
      int px = offn >> 3, c16 = offn & 7;
      const u16* src = gp + (row * 66 + px) * 64 + ((c16 ^ (px & 7)) << 3);
      u16* ldst = lA + ((tid & ~63) + k * 512) * 8;
      __builtin_amdgcn_global_load_lds(
          (const __attribute__((address_space(1))) void*)src,
          (__attribute__((address_space(3))) void*)ldst, 16, 0, 0);
    }
    if (tid < 64) {
      int p = 2048 + tid;
      int row = p / 528, offn = p - row * 528;
      int px = offn >> 3, c16 = offn & 7;
      const u16* src = gp + (row * 66 + px) * 64 + ((c16 ^ (px & 7)) << 3);
      u16* ldst = lA + 2048 * 8;
      __builtin_amdgcn_global_load_lds(
          (const __attribute__((address_space(1))) void*)src,
          (__attribute__((address_space(3))) void*)ldst, 16, 0, 0);
    }
  };
  // skip chunk e (64 ch of xb) -> window rows 0..1, px 1..64
  auto extLoad = [&](int e) {
    #pragma unroll
    for (int k = 0; k < 2; ++k) {
      int i0 = (tid & ~63) + k * 512;          // wave-uniform granule base
      int i = tid + k * 512;
      int ml = i >> 3, c16 = i & 7;
      const u16* src = Xtra + (size_t)(m0 + ml) * 128 + (e << 6) +
                       ((c16 ^ ((ml + 1) & 7)) << 3);
      u16* ldst = lA + (((i0 >> 9) * 66 + ((i0 >> 3) & 63) + 1) << 6);
      __builtin_amdgcn_global_load_lds(
          (const __attribute__((address_space(1))) void*)src,
          (__attribute__((address_space(3))) void*)ldst, 16, 0, 0);
    }
  };

  // ---- precomputed swizzled fragment base pointers ----
  const u16* pA[3][2];
  #pragma unroll
  for (int dx = 0; dx < 3; ++dx)
    #pragma unroll
    for (int h = 0; h < 2; ++h)
      pA[dx][h] = &lA[wm * 4224 + (li + dx) * 64 +
                      ((h * 32 + kq * 8) ^ (((li + dx) & 7) << 3))];
  const u16* pB = lB0 + (wn * 64 + li) * 32 + ((kq * 8) ^ ((li & 3) << 3));

  f32x4 acc[4][4] = {};

  auto compute = [&](int dy, int dx, int h, int buf) {
    short8 af[4], bfv[4];
    #pragma unroll
    for (int f = 0; f < 4; ++f)
      af[f] = *(const short8*)(pA[dx][h] + dy * 4224 + f * 1024);
    #pragma unroll
    for (int f = 0; f < 4; ++f)
      bfv[f] = *(const short8*)(pB + buf * 8192 + f * 512);
    __builtin_amdgcn_s_setprio(1);
    #pragma unroll
    for (int mf = 0; mf < 4; ++mf)
      #pragma unroll
      for (int nf = 0; nf < 4; ++nf)
        acc[mf][nf] = __builtin_amdgcn_mfma_f32_16x16x32_bf16(
            af[mf], bfv[nf], acc[mf][nf], 0, 0, 0);
    __builtin_amdgcn_s_setprio(0);
  };

  // ---- prologue: A chunk 0 + B(0),B(1) ----
  winLoad(0);
  stageB(0, 0);
  stageB(1, 1);
  VM0;
  writeB(0);
  LGKM0; BAR;

  // ---- main chunks ----
  #pragma unroll 1
  for (int c = 0; c < CPS; ++c) {
    #pragma unroll
    for (int hs = 0; hs < 18; ++hs) {
      const int s = c * 18 + hs;
      const int tap = hs >> 1, h = hs & 1;
      const int dy = tap / 3, dx = tap % 3;
      if (s + 2 < NH) stageB(s + 2, h);            // slot (s+2)&1 == h
      if (s + 1 < NH) { VM2; writeB((hs + 1) & 1); }
      compute(dy, dx, h, h);                        // buf = s&1 == h
      LGKM0; BAR;
      if (hs == 17) {
        constexpr bool moreExt = (NEXTRA2 > 0);
        if (c + 1 < CPS) { winLoad(c + 1); VM0; BAR; }
        else if constexpr (moreExt) { extLoad(0); VM0; BAR; }
      }
    }
  }
  // ---- skip chunks (conv2) ----
  if constexpr (NEXTRA2 > 0) {
    #pragma unroll 1
    for (int e = 0; e < NEXTRA2; ++e) {
      #pragma unroll
      for (int hs = 0; hs < 2; ++hs) {
        const int s = 18 * CPS + e * 2 + hs;
        const int h = hs;
        if (s + 2 < NH) stageB(s + 2, h);
        if (s + 1 < NH) { VM2; writeB((hs + 1) & 1); }
        compute(0, 1, h, h);
        LGKM0; BAR;
        if (hs == 1 && e + 1 < NEXTRA2) { extLoad(e + 1); VM0; BAR; }
      }
    }
  }

  const int rb = wm * 64 + 4 * kq;
  const int cb = wn * 64 + li;

  if constexpr (STATS) {
    // write h rows + deterministic per-block BN2 partials
    float ps[4] = {0.f, 0.f, 0.f, 0.f}, pq[4] = {0.f, 0.f, 0.f, 0.f};
    #pragma unroll
    for (int nf = 0; nf < 4; ++nf) {
      int o = cb + nf * 16;
      float al = alpha[o];
      float ta = ADD_TEMB ? temb[b * 256 + o] : 0.f;
      #pragma unroll
      for (int mf = 0; mf < 4; ++mf) {
        #pragma unroll
        for (int r = 0; r < 4; ++r) {
          int m = m0 + rb + mf * 16 + r;
          float v = acc[mf][nf][r] * al + ta;
          outp[(size_t)m * 256 + o] = v;
          ps[nf] += v; pq[nf] += v * v;
        }
      }
    }
    #pragma unroll
    for (int nf = 0; nf < 4; ++nf) {
      ps[nf] += __shfl_xor(ps[nf], 16); ps[nf] += __shfl_xor(ps[nf], 32);
      pq[nf] += __shfl_xor(pq[nf], 16); pq[nf] += __shfl_xor(pq[nf], 32);
    }
    float* reds = (float*)lA;          // [2][256]
    float* redq = reds + 512;
    if (lane < 16) {
      #pragma unroll
      for (int nf = 0; nf < 4; ++nf) {
        reds[wm * 256 + wn * 64 + nf * 16 + lane] = ps[nf];
        redq[wm * 256 + wn * 64 + nf * 16 + lane] = pq[nf];
      }
    }
    __syncthreads();
    if (tid < 256) {
      float s2 = reds[tid] + reds[256 + tid];
      float q2 = redq[tid] + redq[256 + tid];
      pS[(size_t)tid * 1024 + bid] = s2;
      pQ[(size_t)tid * 1024 + bid] = q2;
    }
  } else if constexpr (DIRECT) {
    // LDS transpose -> NCHW coalesced stores straight to out
    float* tb2 = (float*)lA;           // [128][65]
    const int o_l = tid >> 3, xs = (tid & 7) * 16;
    float* obase = outp + (((size_t)(b * 256)) << 12) + (m0 & 4095);
    #pragma unroll 1
    for (int c4 = 0; c4 < 4; ++c4) {
      if (wn == c4) {
        #pragma unroll
        for (int nf = 0; nf < 4; ++nf) {
          float al = alpha[cb + nf * 16];
          #pragma unroll
          for (int mf = 0; mf < 4; ++mf) {
            #pragma unroll
            for (int r = 0; r < 4; ++r)
              tb2[(rb + mf * 16 + r) * 65 + li + nf * 16] = acc[mf][nf][r] * al;
          }
        }
      }
      __syncthreads();
      float* dst = obase + (((size_t)(c4 * 64 + o_l)) << 12) + xs;
      #pragma unroll
      for (int q4 = 0; q4 < 4; ++q4) {
        f32x4 v;
        #pragma unroll
        for (int e = 0; e < 4; ++e) v[e] = tb2[(xs + q4 * 4 + e) * 65 + o_l];
        *(f32x4*)(dst + q4 * 4) = v;
      }
      __syncthreads();
    }
  }
}

extern "C" void kernel_launch(void* const* d_in, const int* in_sizes, int n_in,
                              void* d_out, int out_size, void* d_ws, size_t ws_size,
                              hipStream_t stream) {
  const float* x      = (const float*)d_in[0];
  const float* t      = (const float*)d_in[1];
  const float* w1     = (const float*)d_in[2];
  const float* w2     = (const float*)d_in[3];
  const float* wskip  = (const float*)d_in[4];
  const float* gamma1 = (const float*)d_in[5];
  const float* beta1  = (const float*)d_in[6];
  const float* gamma2 = (const float*)d_in[7];
  const float* beta2  = (const float*)d_in[8];
  const float* tw     = (const float*)d_in[9];
  const float* tb     = (const float*)d_in[10];
  float* out = (float*)d_out;

  uint8_t* base = (uint8_t*)d_ws;
  size_t off = 0;
  auto alloc = [&](size_t bytes) {
    void* p = base + off;
    off += (bytes + 255) & ~(size_t)255;
    return p;
  };
  const size_t szApad = (size_t)32 * 4 * 66 * 66 * 64 * 2; // 128 planes of [66][66][64]
  u16* Apad    = (u16*)alloc(szApad);
  u16* xb      = (u16*)alloc((size_t)131072 * 128 * 2);
  float* h     = (float*)alloc((size_t)131072 * 256 * 4);
  u16* w1s     = (u16*)alloc((size_t)36 * 8192 * 2);
  u16* w2s     = (u16*)alloc((size_t)76 * 8192 * 2);
  float* temb  = (float*)alloc(32 * 256 * 4);
  float* alpha1 = (float*)alloc(256 * 4);
  float* alpha2 = (float*)alloc(256 * 4);
  float* p1    = (float*)alloc(1024 * 4);
  float* pS    = (float*)alloc((size_t)256 * 1024 * 4);
  float* pQ    = (float*)alloc((size_t)256 * 1024 * 4);
  float* sc1   = (float*)alloc(128 * 4);
  float* off1  = (float*)alloc(128 * 4);
  float* sc2   = (float*)alloc(256 * 4);
  float* off2  = (float*)alloc(256 * 4);

  // zero only the plane borders (binact1/binact2 write all interiors)
  border_zero<<<128, 256, 0, stream>>>(Apad);

  bn1_stage1<<<512, 256, 0, stream>>>(x, p1);
  bn1_stage2<<<1, 128, 0, stream>>>(p1, gamma1, beta1, sc1, off1);
  prep_weights<<<256, 256, 0, stream>>>(w1, w2, wskip, w1s, w2s, alpha1, alpha2);
  temb_k<<<32, 256, 0, stream>>>(t, tw, tb, temb);
  binact1<<<2048, 256, 0, stream>>>(x, sc1, off1, Apad, xb);

  // conv1: writes h + BN2 per-block partials
  convk<2, 0, true, true, false><<<1024, 512, 0, stream>>>(
      Apad, xb, w1s, alpha1, temb, h, pS, pQ);

  bn2_stage2b<<<256, 256, 0, stream>>>(pS, pQ, gamma2, beta2, sc2, off2);
  binact2<<<2048, 256, 0, stream>>>(h, sc2, off2, Apad);

  // conv2: direct NCHW output (skip folded into K-tail)
  convk<4, 2, false, false, true><<<1024, 512, 0, stream>>>(
      Apad, xb, w2s, alpha2, (const float*)nullptr, out,
      (float*)nullptr, (float*)nullptr);

  (void)in_sizes; (void)n_in; (void)out_size; (void)ws_size;
}

// Round 7
// 320.053 us; speedup vs baseline: 1.9176x; 1.3643x over previous
//
#include <hip/hip_runtime.h>
#include <stdint.h>

typedef unsigned short u16;
typedef uint8_t u8;
typedef __attribute__((ext_vector_type(8))) short short8;
typedef __attribute__((ext_vector_type(4))) float f32x4;
typedef __attribute__((ext_vector_type(4))) int i32x4;

#define EPSF 1e-5f
#define LGKM0 asm volatile("s_waitcnt lgkmcnt(0)" ::: "memory")
#define VM0   asm volatile("s_waitcnt vmcnt(0)" ::: "memory")
#define VM2   asm volatile("s_waitcnt vmcnt(2)" ::: "memory")
#define BAR   __builtin_amdgcn_s_barrier()
#define GLL(src, dst) __builtin_amdgcn_global_load_lds(                     \
    (const __attribute__((address_space(1))) void*)(src),                   \
    (__attribute__((address_space(3))) void*)(dst), 16, 0, 0)

__device__ __forceinline__ u16 f2bf(float f) {
  uint32_t u = __float_as_uint(f);
  u += 0x7FFFu + ((u >> 16) & 1u);
  return (u16)(u >> 16);
}
__device__ __forceinline__ u16 sgnbf(float y) {
  return y > 0.f ? (u16)0x3F80 : (y < 0.f ? (u16)0xBF80 : (u16)0);
}
__device__ __forceinline__ u8 sgn8(float y) {
  return y > 0.f ? (u8)1 : (y < 0.f ? (u8)0xFF : (u8)0);
}

// ---------------- BN1 stats (x is NCHW f32: 32,128,64,64) ----------------
__global__ void bn1_stage1(const float* __restrict__ x, float* __restrict__ p1) {
  int c = blockIdx.x >> 2, s = blockIdx.x & 3;
  int tid = threadIdx.x;
  float sum = 0.f, sq = 0.f;
  for (int n = s * 8; n < s * 8 + 8; ++n) {
    const f32x4* bp = (const f32x4*)(x + (((size_t)(n * 128 + c)) << 12));
    #pragma unroll 4
    for (int i = tid; i < 1024; i += 256) {
      f32x4 v = bp[i];
      sum += v[0] + v[1] + v[2] + v[3];
      sq  += v[0]*v[0] + v[1]*v[1] + v[2]*v[2] + v[3]*v[3];
    }
  }
  __shared__ float rs[256], rq[256];
  rs[tid] = sum; rq[tid] = sq; __syncthreads();
  for (int st = 128; st > 0; st >>= 1) {
    if (tid < st) { rs[tid] += rs[tid + st]; rq[tid] += rq[tid + st]; }
    __syncthreads();
  }
  if (tid == 0) { p1[blockIdx.x] = rs[0]; p1[512 + blockIdx.x] = rq[0]; }
}

__global__ void bn1_stage2(const float* __restrict__ p1, const float* __restrict__ g,
                           const float* __restrict__ b, float* __restrict__ sc,
                           float* __restrict__ off) {
  int c = threadIdx.x; // 128 threads
  float s = 0.f, q = 0.f;
  for (int k = 0; k < 4; ++k) { s += p1[c * 4 + k]; q += p1[512 + c * 4 + k]; }
  float mean = s * (1.f / 131072.f);
  float var  = q * (1.f / 131072.f) - mean * mean;
  float is = rsqrtf(var + EPSF);
  float scv = g[c] * is;
  sc[c] = scv;
  off[c] = b[c] - mean * scv;
}

// ---------------- BN2 stage2: reduce per-block partials ----------------
__global__ void bn2_stage2b(const float* __restrict__ pS, const float* __restrict__ pQ,
                            const float* __restrict__ g, const float* __restrict__ bb,
                            float* __restrict__ sc, float* __restrict__ off) {
  int o = blockIdx.x, t = threadIdx.x;
  __shared__ float rs[256], rq[256];
  const float* ps = pS + (size_t)o * 1024;
  const float* pq = pQ + (size_t)o * 1024;
  float s = ps[t] + ps[t + 256] + ps[t + 512] + ps[t + 768];
  float q = pq[t] + pq[t + 256] + pq[t + 512] + pq[t + 768];
  rs[t] = s; rq[t] = q; __syncthreads();
  for (int st = 128; st > 0; st >>= 1) {
    if (t < st) { rs[t] += rs[t + st]; rq[t] += rq[t + st]; }
    __syncthreads();
  }
  if (t == 0) {
    float mean = rs[0] * (1.f / 131072.f);
    float var  = rq[0] * (1.f / 131072.f) - mean * mean;
    float is = rsqrtf(var + EPSF);
    float scv = g[o] * is;
    sc[o] = scv;
    off[o] = bb[o] - mean * scv;
  }
}

// ---------------- weight prep ----------------
__device__ __forceinline__ float blk_reduce(float v, float* red) {
  int t = threadIdx.x;
  red[t] = v; __syncthreads();
  for (int st = 128; st > 0; st >>= 1) {
    if (t < st) red[t] += red[t + st];
    __syncthreads();
  }
  float r = red[0]; __syncthreads();
  return r;
}

// i8 step blocks, granule-linear: wS[st][o][64] i8 (byte = st*16384 + o*64 + k).
// conv1: st = tap*2+cc (cc halves of 128ch). conv2: st = c2*18 + tap*2 + cc.
// wskB u16 [2][256][64]: sign(wsk)*ask/alpha2 in bf16.
__global__ void prep_weights(const float* __restrict__ w1, const float* __restrict__ w2,
                             const float* __restrict__ wsk, u8* __restrict__ w1s,
                             u8* __restrict__ w2s, u16* __restrict__ wskB,
                             float* __restrict__ alpha1, float* __restrict__ alpha2) {
  int o = blockIdx.x, t = threadIdx.x;
  __shared__ float red[256];
  float s = 0.f;
  for (int j = t; j < 1152; j += 256) s += fabsf(w1[(size_t)o * 1152 + j]);
  float a1 = blk_reduce(s, red) * (1.f / 1152.f);
  if (t == 0) alpha1[o] = a1;
  for (int j = t; j < 1152; j += 256) {
    int st = j >> 6, k = j & 63;
    int tap = st >> 1, cc = st & 1;
    int ch = cc * 64 + k;
    w1s[(size_t)st * 16384 + o * 64 + k] = sgn8(w1[(size_t)o * 1152 + ch * 9 + tap]);
  }
  s = 0.f;
  for (int j = t; j < 2304; j += 256) s += fabsf(w2[(size_t)o * 2304 + j]);
  float a2 = blk_reduce(s, red) * (1.f / 2304.f);
  if (t == 0) alpha2[o] = a2;
  for (int j = t; j < 2304; j += 256) {
    int st = j >> 6, k = j & 63;
    int c2 = st / 18, r = st % 18, tap = r >> 1, cc = r & 1;
    int ch = c2 * 128 + cc * 64 + k;
    w2s[(size_t)st * 16384 + o * 64 + k] = sgn8(w2[(size_t)o * 2304 + ch * 9 + tap]);
  }
  s = 0.f;
  for (int j = t; j < 128; j += 256) s += fabsf(wsk[o * 128 + j]);
  float ask = blk_reduce(s, red) * (1.f / 128.f);
  float ratio = ask / a2;
  for (int j = t; j < 128; j += 256) {
    int e = j >> 6, k = j & 63;
    float w = wsk[o * 128 + j];
    float v = w > 0.f ? ratio : (w < 0.f ? -ratio : 0.f);
    wskB[(size_t)e * 16384 + o * 64 + k] = f2bf(v);
  }
}

// ---------------- temb = t @ tw^T + tb ----------------
__global__ void temb_k(const float* __restrict__ t, const float* __restrict__ tw,
                       const float* __restrict__ tb, float* __restrict__ temb) {
  int bb = blockIdx.x, o = threadIdx.x;
  __shared__ float tl[512];
  tl[o] = t[bb * 512 + o];
  tl[o + 256] = t[bb * 512 + 256 + o];
  __syncthreads();
  float acc = tb[o];
  #pragma unroll 8
  for (int k = 0; k < 512; ++k) acc += tl[k] * tw[(size_t)o * 512 + k];
  temb[bb * 256 + o] = acc;
}

// ------- border zero: 96 i8 planes of [66][66][128], borders only -------
__global__ void border_zero(u8* __restrict__ Abuf) {
  u8* plane = Abuf + (size_t)blockIdx.x * 557568;
  int tid = threadIdx.x;
  i32x4 z = {};
  for (int idx = tid; idx < 260; idx += 256) {
    int row, px;
    if (idx < 66) { row = 0; px = idx; }
    else if (idx < 132) { row = 65; px = idx - 66; }
    else { int e = idx - 132; row = 1 + (e >> 1); px = (e & 1) * 65; }
    u8* p = plane + (size_t)(row * 66 + px) * 128;
    #pragma unroll
    for (int i = 0; i < 8; ++i) *(i32x4*)(p + i * 16) = z;
  }
}

// -------- binact1: x NCHW -> a1p i8 planes [b][66][66][128] + xb bf16 [m][128] --------
__global__ void binact1(const float* __restrict__ x, const float* __restrict__ sc,
                        const float* __restrict__ off, u8* __restrict__ a1p,
                        u16* __restrict__ xb) {
  int b = blockIdx.x >> 6, y = blockIdx.x & 63, tid = threadIdx.x;
  __shared__ u8  ls[64 * 144];
  __shared__ u16 lx[64 * 136];
  int c = tid >> 1, x0 = (tid & 1) * 32;
  const float* src = x + (((size_t)(b * 128 + c)) << 12) + y * 64 + x0;
  float s0 = sc[c], o0 = off[c];
  #pragma unroll
  for (int i = 0; i < 32; i += 4) {
    f32x4 v = *(const f32x4*)(src + i);
    #pragma unroll
    for (int j = 0; j < 4; ++j) {
      int xc = x0 + i + j;
      float yv = s0 * v[j] + o0;
      ls[xc * 144 + c] = sgn8(yv);
      lx[xc * 136 + c] = f2bf(v[j]);
    }
  }
  __syncthreads();
  int xx = tid >> 2, cg = (tid & 3) * 32;
  u8*  pdst = a1p + ((size_t)b * 4356 + (y + 1) * 66 + xx + 1) * 128 + cg;
  u16* xdst = xb + ((size_t)blockIdx.x * 64 + xx) * 128 + cg;
  *(i32x4*)(pdst)      = *(const i32x4*)&ls[xx * 144 + cg];
  *(i32x4*)(pdst + 16) = *(const i32x4*)&ls[xx * 144 + cg + 16];
  #pragma unroll
  for (int i = 0; i < 32; i += 8)
    *(i32x4*)(xdst + i) = *(const i32x4*)&lx[xx * 136 + cg + i];
}

// -------- binact2: h [m][256] f32 -> a2p i8 planes [b*2+c2][66][66][128] --------
__global__ void binact2(const float* __restrict__ h, const float* __restrict__ sc,
                        const float* __restrict__ off, u8* __restrict__ a2p) {
  int b = blockIdx.x >> 6, y = blockIdx.x & 63, tid = threadIdx.x;
  __shared__ float s_sc[256], s_off[256];
  s_sc[tid] = sc[tid]; s_off[tid] = off[tid];
  __syncthreads();
  const f32x4* src = (const f32x4*)(h + (size_t)blockIdx.x * 16384);
  #pragma unroll 4
  for (int i = tid; i < 4096; i += 256) {
    f32x4 v = src[i];
    int px = i >> 6, c0 = (i & 63) * 4;
    int c2 = c0 >> 7, chm = c0 & 127;
    uint32_t p = (uint32_t)sgn8(s_sc[c0 + 0] * v[0] + s_off[c0 + 0]) |
                 ((uint32_t)sgn8(s_sc[c0 + 1] * v[1] + s_off[c0 + 1]) << 8) |
                 ((uint32_t)sgn8(s_sc[c0 + 2] * v[2] + s_off[c0 + 2]) << 16) |
                 ((uint32_t)sgn8(s_sc[c0 + 3] * v[3] + s_off[c0 + 3]) << 24);
    u8* dst = a2p + ((size_t)(b * 2 + c2) * 4356 + (y + 1) * 66 + px + 1) * 128 + chm;
    *(uint32_t*)dst = p;
  }
}

// ---------------- i8 implicit-GEMM conv ----------------
// M=128 (2 image rows), N=256, 512 thr = 8 waves (2M x 4N), 66.5 KB LDS.
// A: [4][66][128ch] i8 window (all ch of a chunk), 8-slot XOR swizzle via
//    pre-swizzled-source global_load_lds. conv1: loaded once. conv2: 1 reload.
// B: [256][128B] LDS, halves = dbuf; reg-staged 2-deep, counted vmcnt(2),
//    one barrier per K-step (K=64 i8).
// SKIP: 2 bf16 K=64 steps (x * sign(wsk)*ask/alpha2) into float-converted acc.
template <int NCHUNK, bool SKIP, bool ADD_TEMB, bool STATS, bool DIRECT>
__global__ __launch_bounds__(512, 4) void convk(
    const u8* __restrict__ Apl, const u16* __restrict__ xb,
    const u8* __restrict__ wS, const u16* __restrict__ wskB,
    const float* __restrict__ alpha, const float* __restrict__ temb,
    float* __restrict__ outp, float* __restrict__ pS, float* __restrict__ pQ) {
  constexpr int NS = NCHUNK * 18;
  __shared__ u8 lA[33792];
  __shared__ u8 lB[32768];
  const int tid = threadIdx.x;
  const int lane = tid & 63, w = tid >> 6, wm = w >> 2, wn = w & 3;
  const int kq = lane >> 4, li = lane & 15;

  const int bid = blockIdx.x;
  const int tile = (bid & 7) * 128 + (bid >> 3);   // XCD-chunked swizzle
  const int m0 = tile * 128;
  const int b = m0 >> 12, row0 = (m0 >> 6) & 63;

  // ---- B stage: 2 granules/thread/step ----
  i32x4 rB[2][2];
  auto stageB = [&](int s, int slot) {
    const i32x4* g = (const i32x4*)(wS + (size_t)s * 16384) + tid;
    rB[slot][0] = g[0]; rB[slot][1] = g[512];
  };
  auto writeB = [&](int bh) {
    #pragma unroll
    for (int k = 0; k < 2; ++k) {
      int g = tid + k * 512;
      int o = g >> 2, kb = g & 3;
      *(i32x4*)(lB + o * 128 + ((((bh << 2) + kb) ^ (o & 7)) << 4)) = rB[bh][k];
    }
  };

  // ---- A window: 2112 granules, linear dest + pre-swizzled source ----
  auto winLoad = [&](int c) {
    const u8* gp = Apl + (size_t)(b * NCHUNK + c) * 557568 + (size_t)row0 * 8448;
    #pragma unroll
    for (int k = 0; k < 4; ++k) {
      int g = tid + k * 512;
      int row = g / 528, rem = g - row * 528;
      int px = rem >> 3, sl = rem & 7;
      const u8* src = gp + (size_t)(row * 66 + px) * 128 + ((sl ^ (px & 7)) << 4);
      u8* dst = lA + (size_t)((tid & ~63) + k * 512) * 16;
      GLL(src, dst);
    }
    if (tid < 64) {
      int g = 2048 + tid;
      int rem = g - 3 * 528;           // row 3
      int px = rem >> 3, sl = rem & 7;
      const u8* src = gp + (size_t)(3 * 66 + px) * 128 + ((sl ^ (px & 7)) << 4);
      u8* dst = lA + (size_t)2048 * 16;
      GLL(src, dst);
    }
  };

  // ---- fragment base pointers ----
  const u8* pA[3][2];
  #pragma unroll
  for (int dx = 0; dx < 3; ++dx)
    #pragma unroll
    for (int cc = 0; cc < 2; ++cc)
      pA[dx][cc] = lA + (size_t)wm * 8448 + (li + dx) * 128 +
                   ((((cc << 2) + kq) ^ ((li + dx) & 7)) << 4);
  const u8* pB2[2];
  #pragma unroll
  for (int bh = 0; bh < 2; ++bh)
    pB2[bh] = lB + (wn * 64 + li) * 128 + ((((bh << 2) + kq) ^ (li & 7)) << 4);

  i32x4 acc[4][4] = {};

  auto compute = [&](int dy, int dx, int cc, int bh) {
    i32x4 av[4], bv[4];
    #pragma unroll
    for (int f = 0; f < 4; ++f)
      av[f] = *(const i32x4*)(pA[dx][cc] + dy * 8448 + f * 2048);
    #pragma unroll
    for (int f = 0; f < 4; ++f)
      bv[f] = *(const i32x4*)(pB2[bh] + f * 2048);
    __builtin_amdgcn_s_setprio(1);
    #pragma unroll
    for (int mf = 0; mf < 4; ++mf)
      #pragma unroll
      for (int nf = 0; nf < 4; ++nf)
        acc[mf][nf] = __builtin_amdgcn_mfma_i32_16x16x64_i8(
            av[mf], bv[nf], acc[mf][nf], 0, 0, 0);
    __builtin_amdgcn_s_setprio(0);
  };

  // ---- prologue ----
  winLoad(0);
  stageB(0, 0);
  stageB(1, 1);
  VM0;
  writeB(0);
  LGKM0; BAR;

  // ---- main loop: one barrier per K-step ----
  #pragma unroll
  for (int s = 0; s < NS; ++s) {
    const int t = s % 18, cc = t & 1, tap = t >> 1;
    const int dy = tap / 3, dx = tap % 3;
    if (s + 2 < NS) stageB(s + 2, s & 1);
    if (s + 1 < NS) {
      if (s + 2 < NS) { VM2; } else { VM0; }
      writeB((s + 1) & 1);
    }
    compute(dy, dx, cc, s & 1);
    LGKM0; BAR;
    if (t == 17 && s + 1 < NS) { winLoad((s + 1) / 18); VM0; BAR; }
  }

  f32x4 facc[4][4];
  if constexpr (SKIP) {
    #pragma unroll
    for (int mf = 0; mf < 4; ++mf)
      #pragma unroll
      for (int nf = 0; nf < 4; ++nf)
        #pragma unroll
        for (int r = 0; r < 4; ++r)
          facc[mf][nf][r] = (float)acc[mf][nf][r];
    const u8* pAs[2];
    const u8* pBs[2];
    #pragma unroll
    for (int ks = 0; ks < 2; ++ks) {
      pAs[ks] = lA + (wm * 64 + li) * 128 + ((((ks << 2) + kq) ^ (li & 7)) << 4);
      pBs[ks] = lB + (wn * 64 + li) * 128 + ((((ks << 2) + kq) ^ (li & 7)) << 4);
    }
    #pragma unroll
    for (int e = 0; e < 2; ++e) {
      // stage skip-A (xb, pre-swizzled source) into lA
      #pragma unroll
      for (int k = 0; k < 2; ++k) {
        int g = tid + k * 512;
        int m = g >> 3, sl = g & 7;
        const u8* src = (const u8*)xb + (size_t)(m0 + m) * 256 + e * 128 +
                        ((sl ^ (m & 7)) << 4);
        u8* dst = lA + (size_t)((tid & ~63) + k * 512) * 16;
        GLL(src, dst);
      }
      // stage skip-B into regs then swizzled LDS
      i32x4 rS[4];
      const i32x4* gs = (const i32x4*)((const u8*)wskB + (size_t)e * 32768) + tid;
      #pragma unroll
      for (int k = 0; k < 4; ++k) rS[k] = gs[k * 512];
      VM0;
      #pragma unroll
      for (int k = 0; k < 4; ++k) {
        int g = tid + k * 512;
        int o = g >> 3, sl = g & 7;
        *(i32x4*)(lB + o * 128 + ((sl ^ (o & 7)) << 4)) = rS[k];
      }
      LGKM0; BAR;
      #pragma unroll
      for (int ks = 0; ks < 2; ++ks) {
        short8 av[4], bv[4];
        #pragma unroll
        for (int f = 0; f < 4; ++f) av[f] = *(const short8*)(pAs[ks] + f * 2048);
        #pragma unroll
        for (int f = 0; f < 4; ++f) bv[f] = *(const short8*)(pBs[ks] + f * 2048);
        __builtin_amdgcn_s_setprio(1);
        #pragma unroll
        for (int mf = 0; mf < 4; ++mf)
          #pragma unroll
          for (int nf = 0; nf < 4; ++nf)
            facc[mf][nf] = __builtin_amdgcn_mfma_f32_16x16x32_bf16(
                av[mf], bv[nf], facc[mf][nf], 0, 0, 0);
        __builtin_amdgcn_s_setprio(0);
      }
      if (e == 0) { LGKM0; BAR; }
    }
    LGKM0; BAR;
  }

  const int rb = wm * 64 + 4 * kq;
  const int cb = wn * 64 + li;

  if constexpr (STATS) {
    float ps[4] = {0.f, 0.f, 0.f, 0.f}, pq[4] = {0.f, 0.f, 0.f, 0.f};
    #pragma unroll
    for (int nf = 0; nf < 4; ++nf) {
      int o = cb + nf * 16;
      float al = alpha[o];
      float ta = ADD_TEMB ? temb[b * 256 + o] : 0.f;
      #pragma unroll
      for (int mf = 0; mf < 4; ++mf) {
        #pragma unroll
        for (int r = 0; r < 4; ++r) {
          int m = m0 + rb + mf * 16 + r;
          float v = (float)acc[mf][nf][r] * al + ta;
          outp[(size_t)m * 256 + o] = v;
          ps[nf] += v; pq[nf] += v * v;
        }
      }
    }
    #pragma unroll
    for (int nf = 0; nf < 4; ++nf) {
      ps[nf] += __shfl_xor(ps[nf], 16); ps[nf] += __shfl_xor(ps[nf], 32);
      pq[nf] += __shfl_xor(pq[nf], 16); pq[nf] += __shfl_xor(pq[nf], 32);
    }
    float* reds = (float*)lA;          // [2][256]
    float* redq = reds + 512;
    __syncthreads();
    if (lane < 16) {
      #pragma unroll
      for (int nf = 0; nf < 4; ++nf) {
        reds[wm * 256 + wn * 64 + nf * 16 + lane] = ps[nf];
        redq[wm * 256 + wn * 64 + nf * 16 + lane] = pq[nf];
      }
    }
    __syncthreads();
    if (tid < 256) {
      pS[(size_t)tid * 1024 + bid] = reds[tid] + reds[256 + tid];
      pQ[(size_t)tid * 1024 + bid] = redq[tid] + redq[256 + tid];
    }
  } else if constexpr (DIRECT) {
    float* tb2 = (float*)lA;           // [128][65]
    const int o_l = tid >> 3, xs = (tid & 7) * 16;
    float* obase = outp + (((size_t)(b * 256)) << 12) + (m0 & 4095);
    #pragma unroll 1
    for (int c4 = 0; c4 < 4; ++c4) {
      if (wn == c4) {
        #pragma unroll
        for (int nf = 0; nf < 4; ++nf) {
          float al = alpha[cb + nf * 16];
          #pragma unroll
          for (int mf = 0; mf < 4; ++mf) {
            #pragma unroll
            for (int r = 0; r < 4; ++r)
              tb2[(rb + mf * 16 + r) * 65 + li + nf * 16] = facc[mf][nf][r] * al;
          }
        }
      }
      __syncthreads();
      float* dst = obase + (((size_t)(c4 * 64 + o_l)) << 12) + xs;
      #pragma unroll
      for (int q4 = 0; q4 < 4; ++q4) {
        f32x4 v;
        #pragma unroll
        for (int e = 0; e < 4; ++e) v[e] = tb2[(xs + q4 * 4 + e) * 65 + o_l];
        *(f32x4*)(dst + q4 * 4) = v;
      }
      __syncthreads();
    }
  }
}

extern "C" void kernel_launch(void* const* d_in, const int* in_sizes, int n_in,
                              void* d_out, int out_size, void* d_ws, size_t ws_size,
                              hipStream_t stream) {
  const float* x      = (const float*)d_in[0];
  const float* t      = (const float*)d_in[1];
  const float* w1     = (const float*)d_in[2];
  const float* w2     = (const float*)d_in[3];
  const float* wskip  = (const float*)d_in[4];
  const float* gamma1 = (const float*)d_in[5];
  const float* beta1  = (const float*)d_in[6];
  const float* gamma2 = (const float*)d_in[7];
  const float* beta2  = (const float*)d_in[8];
  const float* tw     = (const float*)d_in[9];
  const float* tb     = (const float*)d_in[10];
  float* out = (float*)d_out;

  uint8_t* base = (uint8_t*)d_ws;
  size_t off = 0;
  auto alloc = [&](size_t bytes) {
    void* p = base + off;
    off += (bytes + 255) & ~(size_t)255;
    return p;
  };
  // 96 i8 planes of [66][66][128]: first 32 = a1p, next 64 = a2p
  u8* Abuf     = (u8*)alloc((size_t)96 * 557568);
  u8* a1p      = Abuf;
  u8* a2p      = Abuf + (size_t)32 * 557568;
  u16* xb      = (u16*)alloc((size_t)131072 * 128 * 2);
  float* h     = (float*)alloc((size_t)131072 * 256 * 4);
  u8* w1s      = (u8*)alloc((size_t)18 * 16384);
  u8* w2s      = (u8*)alloc((size_t)36 * 16384);
  u16* wskB    = (u16*)alloc((size_t)2 * 16384 * 2);
  float* temb  = (float*)alloc(32 * 256 * 4);
  float* alpha1 = (float*)alloc(256 * 4);
  float* alpha2 = (float*)alloc(256 * 4);
  float* p1    = (float*)alloc(1024 * 4);
  float* pS    = (float*)alloc((size_t)256 * 1024 * 4);
  float* pQ    = (float*)alloc((size_t)256 * 1024 * 4);
  float* sc1   = (float*)alloc(128 * 4);
  float* off1  = (float*)alloc(128 * 4);
  float* sc2   = (float*)alloc(256 * 4);
  float* off2  = (float*)alloc(256 * 4);

  border_zero<<<96, 256, 0, stream>>>(Abuf);

  bn1_stage1<<<512, 256, 0, stream>>>(x, p1);
  bn1_stage2<<<1, 128, 0, stream>>>(p1, gamma1, beta1, sc1, off1);
  prep_weights<<<256, 256, 0, stream>>>(w1, w2, wskip, w1s, w2s, wskB, alpha1, alpha2);
  temb_k<<<32, 256, 0, stream>>>(t, tw, tb, temb);
  binact1<<<2048, 256, 0, stream>>>(x, sc1, off1, a1p, xb);

  // conv1: i8, writes h + BN2 per-block partials
  convk<1, false, true, true, false><<<1024, 512, 0, stream>>>(
      a1p, xb, w1s, (const u16*)nullptr, alpha1, temb, h, pS, pQ);

  bn2_stage2b<<<256, 256, 0, stream>>>(pS, pQ, gamma2, beta2, sc2, off2);
  binact2<<<2048, 256, 0, stream>>>(h, sc2, off2, a2p);

  // conv2: i8 + bf16 skip tail, direct NCHW output
  convk<2, true, false, false, true><<<1024, 512, 0, stream>>>(
      a2p, xb, w2s, wskB, alpha2, (const float*)nullptr, out,
      (float*)nullptr, (float*)nullptr);

  (void)in_sizes; (void)n_in; (void)out_size; (void)ws_size;
}

// Round 8
// 306.617 us; speedup vs baseline: 2.0017x; 1.0438x over previous
//
#include <hip/hip_runtime.h>
#include <stdint.h>

typedef unsigned short u16;
typedef uint8_t u8;
typedef __attribute__((ext_vector_type(8))) short short8;
typedef __attribute__((ext_vector_type(4))) float f32x4;
typedef __attribute__((ext_vector_type(4))) int i32x4;

#define EPSF 1e-5f
#define LGKM0 asm volatile("s_waitcnt lgkmcnt(0)" ::: "memory")
#define VM0   asm volatile("s_waitcnt vmcnt(0)" ::: "memory")
#define VM4   asm volatile("s_waitcnt vmcnt(4)" ::: "memory")
#define BAR   __builtin_amdgcn_s_barrier()
#define GLL(src, dst) __builtin_amdgcn_global_load_lds(                     \
    (const __attribute__((address_space(1))) void*)(src),                   \
    (__attribute__((address_space(3))) void*)(dst), 16, 0, 0)

__device__ __forceinline__ u16 f2bf(float f) {
  uint32_t u = __float_as_uint(f);
  u += 0x7FFFu + ((u >> 16) & 1u);
  return (u16)(u >> 16);
}
__device__ __forceinline__ u8 sgn8(float y) {
  return y > 0.f ? (u8)1 : (y < 0.f ? (u8)0xFF : (u8)0);
}

// ---------------- BN1 stats (x is NCHW f32: 32,128,64,64) ----------------
__global__ void bn1_stage1(const float* __restrict__ x, float* __restrict__ p1) {
  int c = blockIdx.x >> 2, s = blockIdx.x & 3;
  int tid = threadIdx.x;
  float sum = 0.f, sq = 0.f;
  for (int n = s * 8; n < s * 8 + 8; ++n) {
    const f32x4* bp = (const f32x4*)(x + (((size_t)(n * 128 + c)) << 12));
    #pragma unroll 4
    for (int i = tid; i < 1024; i += 256) {
      f32x4 v = bp[i];
      sum += v[0] + v[1] + v[2] + v[3];
      sq  += v[0]*v[0] + v[1]*v[1] + v[2]*v[2] + v[3]*v[3];
    }
  }
  __shared__ float rs[256], rq[256];
  rs[tid] = sum; rq[tid] = sq; __syncthreads();
  for (int st = 128; st > 0; st >>= 1) {
    if (tid < st) { rs[tid] += rs[tid + st]; rq[tid] += rq[tid + st]; }
    __syncthreads();
  }
  if (tid == 0) { p1[blockIdx.x] = rs[0]; p1[512 + blockIdx.x] = rq[0]; }
}

__global__ void bn1_stage2(const float* __restrict__ p1, const float* __restrict__ g,
                           const float* __restrict__ b, float* __restrict__ sc,
                           float* __restrict__ off) {
  int c = threadIdx.x; // 128 threads
  float s = 0.f, q = 0.f;
  for (int k = 0; k < 4; ++k) { s += p1[c * 4 + k]; q += p1[512 + c * 4 + k]; }
  float mean = s * (1.f / 131072.f);
  float var  = q * (1.f / 131072.f) - mean * mean;
  float is = rsqrtf(var + EPSF);
  float scv = g[c] * is;
  sc[c] = scv;
  off[c] = b[c] - mean * scv;
}

// ---------------- BN2 stage2: reduce per-block partials ----------------
__global__ void bn2_stage2b(const float* __restrict__ pS, const float* __restrict__ pQ,
                            const float* __restrict__ g, const float* __restrict__ bb,
                            float* __restrict__ sc, float* __restrict__ off) {
  int o = blockIdx.x, t = threadIdx.x;
  __shared__ float rs[256], rq[256];
  const float* ps = pS + (size_t)o * 1024;
  const float* pq = pQ + (size_t)o * 1024;
  float s = ps[t] + ps[t + 256] + ps[t + 512] + ps[t + 768];
  float q = pq[t] + pq[t + 256] + pq[t + 512] + pq[t + 768];
  rs[t] = s; rq[t] = q; __syncthreads();
  for (int st = 128; st > 0; st >>= 1) {
    if (t < st) { rs[t] += rs[t + st]; rq[t] += rq[t + st]; }
    __syncthreads();
  }
  if (t == 0) {
    float mean = rs[0] * (1.f / 131072.f);
    float var  = rq[0] * (1.f / 131072.f) - mean * mean;
    float is = rsqrtf(var + EPSF);
    float scv = g[o] * is;
    sc[o] = scv;
    off[o] = bb[o] - mean * scv;
  }
}

// ---------------- weight prep ----------------
__device__ __forceinline__ float blk_reduce(float v, float* red) {
  int t = threadIdx.x;
  red[t] = v; __syncthreads();
  for (int st = 128; st > 0; st >>= 1) {
    if (t < st) red[t] += red[t + st];
    __syncthreads();
  }
  float r = red[0]; __syncthreads();
  return r;
}

// i8 step blocks packed for region-owned global_load_lds:
// byte(st, rg, g, j) with g = (o_loc<<2) + ((k>>4) ^ (o_loc&3)), j = k&15
// holds w[o = rg*64+o_loc][k] for the step's 64-ch slice.
// conv1: st = tap*2+cc (cc halves of 128ch). conv2: st = c2*18 + tap*2 + cc.
// wskB u16 [2][256][64]: sign(wsk)*ask/alpha2 in bf16 (granule-linear o*64+k).
__global__ void prep_weights(const float* __restrict__ w1, const float* __restrict__ w2,
                             const float* __restrict__ wsk, u8* __restrict__ w1s,
                             u8* __restrict__ w2s, u16* __restrict__ wskB,
                             float* __restrict__ alpha1, float* __restrict__ alpha2) {
  int o = blockIdx.x, t = threadIdx.x;
  int rg = o >> 6, ol = o & 63;
  __shared__ float red[256];
  float s = 0.f;
  for (int j = t; j < 1152; j += 256) s += fabsf(w1[(size_t)o * 1152 + j]);
  float a1 = blk_reduce(s, red) * (1.f / 1152.f);
  if (t == 0) alpha1[o] = a1;
  for (int j = t; j < 1152; j += 256) {
    int st = j >> 6, k = j & 63;
    int tap = st >> 1, cc = st & 1;
    int ch = cc * 64 + k;
    int g = (ol << 2) + ((k >> 4) ^ (ol & 3));
    w1s[(size_t)st * 16384 + rg * 4096 + g * 16 + (k & 15)] =
        sgn8(w1[(size_t)o * 1152 + ch * 9 + tap]);
  }
  s = 0.f;
  for (int j = t; j < 2304; j += 256) s += fabsf(w2[(size_t)o * 2304 + j]);
  float a2 = blk_reduce(s, red) * (1.f / 2304.f);
  if (t == 0) alpha2[o] = a2;
  for (int j = t; j < 2304; j += 256) {
    int st = j >> 6, k = j & 63;
    int c2 = st / 18, r = st % 18, tap = r >> 1, cc = r & 1;
    int ch = c2 * 128 + cc * 64 + k;
    int g = (ol << 2) + ((k >> 4) ^ (ol & 3));
    w2s[(size_t)st * 16384 + rg * 4096 + g * 16 + (k & 15)] =
        sgn8(w2[(size_t)o * 2304 + ch * 9 + tap]);
  }
  s = 0.f;
  for (int j = t; j < 128; j += 256) s += fabsf(wsk[o * 128 + j]);
  float ask = blk_reduce(s, red) * (1.f / 128.f);
  float ratio = ask / a2;
  for (int j = t; j < 128; j += 256) {
    int e = j >> 6, k = j & 63;
    float w = wsk[o * 128 + j];
    float v = w > 0.f ? ratio : (w < 0.f ? -ratio : 0.f);
    wskB[(size_t)e * 16384 + o * 64 + k] = f2bf(v);
  }
}

// ---------------- temb = t @ tw^T + tb ----------------
__global__ void temb_k(const float* __restrict__ t, const float* __restrict__ tw,
                       const float* __restrict__ tb, float* __restrict__ temb) {
  int bb = blockIdx.x, o = threadIdx.x;
  __shared__ float tl[512];
  tl[o] = t[bb * 512 + o];
  tl[o + 256] = t[bb * 512 + 256 + o];
  __syncthreads();
  float acc = tb[o];
  #pragma unroll 8
  for (int k = 0; k < 512; ++k) acc += tl[k] * tw[(size_t)o * 512 + k];
  temb[bb * 256 + o] = acc;
}

// ------- border zero: 96 i8 planes of [66][66][128], borders only -------
__global__ void border_zero(u8* __restrict__ Abuf) {
  u8* plane = Abuf + (size_t)blockIdx.x * 557568;
  int tid = threadIdx.x;
  i32x4 z = {};
  for (int idx = tid; idx < 260; idx += 256) {
    int row, px;
    if (idx < 66) { row = 0; px = idx; }
    else if (idx < 132) { row = 65; px = idx - 66; }
    else { int e = idx - 132; row = 1 + (e >> 1); px = (e & 1) * 65; }
    u8* p = plane + (size_t)(row * 66 + px) * 128;
    #pragma unroll
    for (int i = 0; i < 8; ++i) *(i32x4*)(p + i * 16) = z;
  }
}

// -------- binact1: x NCHW -> a1p i8 planes [b][66][66][128] + xb bf16 [m][128] --------
__global__ void binact1(const float* __restrict__ x, const float* __restrict__ sc,
                        const float* __restrict__ off, u8* __restrict__ a1p,
                        u16* __restrict__ xb) {
  int b = blockIdx.x >> 6, y = blockIdx.x & 63, tid = threadIdx.x;
  __shared__ u8  ls[64 * 144];
  __shared__ u16 lx[64 * 136];
  int c = tid >> 1, x0 = (tid & 1) * 32;
  const float* src = x + (((size_t)(b * 128 + c)) << 12) + y * 64 + x0;
  float s0 = sc[c], o0 = off[c];
  #pragma unroll
  for (int i = 0; i < 32; i += 4) {
    f32x4 v = *(const f32x4*)(src + i);
    #pragma unroll
    for (int j = 0; j < 4; ++j) {
      int xc = x0 + i + j;
      float yv = s0 * v[j] + o0;
      ls[xc * 144 + c] = sgn8(yv);
      lx[xc * 136 + c] = f2bf(v[j]);
    }
  }
  __syncthreads();
  int xx = tid >> 2, cg = (tid & 3) * 32;
  u8*  pdst = a1p + ((size_t)b * 4356 + (y + 1) * 66 + xx + 1) * 128 + cg;
  u16* xdst = xb + ((size_t)blockIdx.x * 64 + xx) * 128 + cg;
  *(i32x4*)(pdst)      = *(const i32x4*)&ls[xx * 144 + cg];
  *(i32x4*)(pdst + 16) = *(const i32x4*)&ls[xx * 144 + cg + 16];
  #pragma unroll
  for (int i = 0; i < 32; i += 8)
    *(i32x4*)(xdst + i) = *(const i32x4*)&lx[xx * 136 + cg + i];
}

// -------- binact2: h [m][256] f32 -> a2p i8 planes [b*2+c2][66][66][128] --------
__global__ void binact2(const float* __restrict__ h, const float* __restrict__ sc,
                        const float* __restrict__ off, u8* __restrict__ a2p) {
  int b = blockIdx.x >> 6, y = blockIdx.x & 63, tid = threadIdx.x;
  __shared__ float s_sc[256], s_off[256];
  s_sc[tid] = sc[tid]; s_off[tid] = off[tid];
  __syncthreads();
  const f32x4* src = (const f32x4*)(h + (size_t)blockIdx.x * 16384);
  #pragma unroll 4
  for (int i = tid; i < 4096; i += 256) {
    f32x4 v = src[i];
    int px = i >> 6, c0 = (i & 63) * 4;
    int c2 = c0 >> 7, chm = c0 & 127;
    uint32_t p = (uint32_t)sgn8(s_sc[c0 + 0] * v[0] + s_off[c0 + 0]) |
                 ((uint32_t)sgn8(s_sc[c0 + 1] * v[1] + s_off[c0 + 1]) << 8) |
                 ((uint32_t)sgn8(s_sc[c0 + 2] * v[2] + s_off[c0 + 2]) << 16) |
                 ((uint32_t)sgn8(s_sc[c0 + 3] * v[3] + s_off[c0 + 3]) << 24);
    u8* dst = a2p + ((size_t)(b * 2 + c2) * 4356 + (y + 1) * 66 + px + 1) * 128 + chm;
    *(uint32_t*)dst = p;
  }
}

// ---------------- i8 implicit-GEMM conv ----------------
// M=128, N=256, 512 thr = 8 waves (2M x 4N), 66.5 KB LDS, 2 blocks/CU.
// A: [4][66][128ch] i8 window, 8-slot XOR swizzle via pre-swizzled-source GLL.
// B: owned-region GLL, [2][4 regions][64 rows x 64B] with 4-slot swizzle baked
//    into the pack; 1 barrier + vmcnt(4) + lgkmcnt(0) per K-step, no ds_write.
// Epilogues restage through LDS for full-line coalesced global stores.
template <int NCHUNK, bool SKIP, bool ADD_TEMB, bool STATS, bool DIRECT>
__global__ __launch_bounds__(512, 4) void convk(
    const u8* __restrict__ Apl, const u16* __restrict__ xb,
    const u8* __restrict__ wS, const u16* __restrict__ wskB,
    const float* __restrict__ alpha, const float* __restrict__ temb,
    float* __restrict__ outp, float* __restrict__ pS, float* __restrict__ pQ) {
  constexpr int NS = NCHUNK * 18;
  __shared__ u8 smem[66560];
  u8* lA = smem;            // 33792 B
  u8* lB = smem + 33792;    // 2 x 16384 B
  const int tid = threadIdx.x;
  const int lane = tid & 63, w = tid >> 6, wm = w >> 2, wn = w & 3;
  const int kq = lane >> 4, li = lane & 15;

  const int bid = blockIdx.x;
  const int tile = (bid & 7) * 128 + (bid >> 3);   // XCD-chunked swizzle
  const int m0 = tile * 128;
  const int b = m0 >> 12, row0 = (m0 >> 6) & 63;

  // ---- B: owned-region GLL (waves w and w+4 duplicate identically) ----
  auto issueB = [&](int s) {
    const u8* src = wS + (size_t)s * 16384 + wn * 4096 + lane * 16;
    u8* dst = lB + (s & 1) * 16384 + wn * 4096;
    #pragma unroll
    for (int i = 0; i < 4; ++i) GLL(src + i * 1024, dst + i * 1024);
  };

  // ---- A window: 2112 granules, linear dest + pre-swizzled source ----
  auto winLoad = [&](int c) {
    const u8* gp = Apl + (size_t)(b * NCHUNK + c) * 557568 + (size_t)row0 * 8448;
    #pragma unroll
    for (int k = 0; k < 4; ++k) {
      int g = tid + k * 512;
      int row = g / 528, rem = g - row * 528;
      int px = rem >> 3, sl = rem & 7;
      const u8* src = gp + (size_t)(row * 66 + px) * 128 + ((sl ^ (px & 7)) << 4);
      u8* dst = lA + (size_t)((tid & ~63) + k * 512) * 16;
      GLL(src, dst);
    }
    if (tid < 64) {
      int g = 2048 + tid;
      int rem = g - 3 * 528;           // row 3
      int px = rem >> 3, sl = rem & 7;
      const u8* src = gp + (size_t)(3 * 66 + px) * 128 + ((sl ^ (px & 7)) << 4);
      u8* dst = lA + (size_t)2048 * 16;
      GLL(src, dst);
    }
  };

  // ---- fragment base pointers ----
  const u8* pA[3][2];
  #pragma unroll
  for (int dx = 0; dx < 3; ++dx)
    #pragma unroll
    for (int cc = 0; cc < 2; ++cc)
      pA[dx][cc] = lA + (size_t)wm * 8448 + (li + dx) * 128 +
                   ((((cc << 2) + kq) ^ ((li + dx) & 7)) << 4);
  const u8* pB = lB + wn * 4096 + li * 64 + ((kq ^ (li & 3)) << 4);

  i32x4 acc[4][4] = {};

  auto compute = [&](int dy, int dx, int cc, int buf) {
    i32x4 av[4], bv[4];
    #pragma unroll
    for (int f = 0; f < 4; ++f)
      av[f] = *(const i32x4*)(pA[dx][cc] + dy * 8448 + f * 2048);
    #pragma unroll
    for (int f = 0; f < 4; ++f)
      bv[f] = *(const i32x4*)(pB + buf * 16384 + f * 1024);
    __builtin_amdgcn_s_setprio(1);
    #pragma unroll
    for (int mf = 0; mf < 4; ++mf)
      #pragma unroll
      for (int nf = 0; nf < 4; ++nf)
        acc[mf][nf] = __builtin_amdgcn_mfma_i32_16x16x64_i8(
            av[mf], bv[nf], acc[mf][nf], 0, 0, 0);
    __builtin_amdgcn_s_setprio(0);
  };

  // ---- prologue: A chunk 0 + B(0) ----
  winLoad(0);
  issueB(0);

  // ---- main loop: 1 barrier per K-step ----
  #pragma unroll
  for (int s = 0; s < NS; ++s) {
    const int t = s % 18, cc = t & 1, tap = t >> 1;
    if (s + 1 < NS) issueB(s + 1);
    if (s + 1 < NS) { VM4; } else { VM0; }
    if (t == 0) BAR;                  // publish A window (and B at s==0)
    compute(tap / 3, tap % 3, cc, s & 1);
    LGKM0; BAR;
    if (t == 17 && s + 1 < NS) winLoad((s + 1) / 18);
  }

  f32x4 facc[4][4];
  if constexpr (SKIP) {
    #pragma unroll
    for (int mf = 0; mf < 4; ++mf)
      #pragma unroll
      for (int nf = 0; nf < 4; ++nf)
        #pragma unroll
        for (int r = 0; r < 4; ++r)
          facc[mf][nf][r] = (float)acc[mf][nf][r];
    const u8* pAs[2];
    const u8* pBs[2];
    #pragma unroll
    for (int ks = 0; ks < 2; ++ks) {
      pAs[ks] = lA + (wm * 64 + li) * 128 + ((((ks << 2) + kq) ^ (li & 7)) << 4);
      pBs[ks] = lB + (wn * 64 + li) * 128 + ((((ks << 2) + kq) ^ (li & 7)) << 4);
    }
    #pragma unroll
    for (int e = 0; e < 2; ++e) {
      // stage skip-A (xb, pre-swizzled source) into lA
      #pragma unroll
      for (int k = 0; k < 2; ++k) {
        int g = tid + k * 512;
        int m = g >> 3, sl = g & 7;
        const u8* src = (const u8*)xb + (size_t)(m0 + m) * 256 + e * 128 +
                        ((sl ^ (m & 7)) << 4);
        u8* dst = lA + (size_t)((tid & ~63) + k * 512) * 16;
        GLL(src, dst);
      }
      // stage skip-B into regs then swizzled LDS
      i32x4 rS[4];
      const i32x4* gs = (const i32x4*)((const u8*)wskB + (size_t)e * 32768) + tid;
      #pragma unroll
      for (int k = 0; k < 4; ++k) rS[k] = gs[k * 512];
      VM0;
      #pragma unroll
      for (int k = 0; k < 4; ++k) {
        int g = tid + k * 512;
        int o = g >> 3, sl = g & 7;
        *(i32x4*)(lB + o * 128 + ((sl ^ (o & 7)) << 4)) = rS[k];
      }
      LGKM0; BAR;
      #pragma unroll
      for (int ks = 0; ks < 2; ++ks) {
        short8 av[4], bv[4];
        #pragma unroll
        for (int f = 0; f < 4; ++f) av[f] = *(const short8*)(pAs[ks] + f * 2048);
        #pragma unroll
        for (int f = 0; f < 4; ++f) bv[f] = *(const short8*)(pBs[ks] + f * 2048);
        __builtin_amdgcn_s_setprio(1);
        #pragma unroll
        for (int mf = 0; mf < 4; ++mf)
          #pragma unroll
          for (int nf = 0; nf < 4; ++nf)
            facc[mf][nf] = __builtin_amdgcn_mfma_f32_16x16x32_bf16(
                av[mf], bv[nf], facc[mf][nf], 0, 0, 0);
        __builtin_amdgcn_s_setprio(0);
      }
      if (e == 0) { LGKM0; BAR; }
    }
    LGKM0; BAR;
  }

  const int cb = wn * 64 + li;

  if constexpr (STATS) {
    // per-block BN2 partials from registers (deterministic)
    float als[4], tas[4];
    #pragma unroll
    for (int nf = 0; nf < 4; ++nf) {
      int o = cb + nf * 16;
      als[nf] = alpha[o];
      tas[nf] = ADD_TEMB ? temb[b * 256 + o] : 0.f;
    }
    float ps[4] = {0.f, 0.f, 0.f, 0.f}, pq[4] = {0.f, 0.f, 0.f, 0.f};
    #pragma unroll
    for (int nf = 0; nf < 4; ++nf)
      #pragma unroll
      for (int mf = 0; mf < 4; ++mf)
        #pragma unroll
        for (int r = 0; r < 4; ++r) {
          float v = (float)acc[mf][nf][r] * als[nf] + tas[nf];
          ps[nf] += v; pq[nf] += v * v;
        }
    #pragma unroll
    for (int nf = 0; nf < 4; ++nf) {
      ps[nf] += __shfl_xor(ps[nf], 16); ps[nf] += __shfl_xor(ps[nf], 32);
      pq[nf] += __shfl_xor(pq[nf], 16); pq[nf] += __shfl_xor(pq[nf], 32);
    }
    float* reds = (float*)smem;        // [2][256]
    float* redq = reds + 512;
    __syncthreads();
    if (lane < 16) {
      #pragma unroll
      for (int nf = 0; nf < 4; ++nf) {
        reds[wm * 256 + wn * 64 + nf * 16 + lane] = ps[nf];
        redq[wm * 256 + wn * 64 + nf * 16 + lane] = pq[nf];
      }
    }
    __syncthreads();
    if (tid < 256) {
      pS[(size_t)tid * 1024 + bid] = reds[tid] + reds[256 + tid];
      pQ[(size_t)tid * 1024 + bid] = redq[tid] + redq[256 + tid];
    }
    __syncthreads();
    // restage h tile through LDS for full-line coalesced stores
    float* ld = (float*)smem;          // [64][256] granule-XOR swizzled
    #pragma unroll 1
    for (int p = 0; p < 2; ++p) {
      if (wm == p) {
        #pragma unroll
        for (int nf = 0; nf < 4; ++nf) {
          int colg0 = (cb + nf * 16) >> 2, c3 = li & 3;
          #pragma unroll
          for (int mf = 0; mf < 4; ++mf)
            #pragma unroll
            for (int r = 0; r < 4; ++r) {
              int rloc = mf * 16 + 4 * kq + r;
              float v = (float)acc[mf][nf][r] * als[nf] + tas[nf];
              ld[rloc * 256 + ((colg0 ^ kq) << 2) + c3] = v;
            }
        }
      }
      __syncthreads();
      #pragma unroll
      for (int it = 0; it < 8; ++it) {
        int flat = tid + it * 512;
        int row = flat >> 6, c4 = flat & 63;
        int c4p = c4 ^ ((row >> 2) & 3);
        f32x4 v = *(const f32x4*)&ld[row * 256 + c4p * 4];
        *(f32x4*)(outp + (size_t)(m0 + p * 64 + row) * 256 + c4 * 4) = v;
      }
      __syncthreads();
    }
  } else if constexpr (DIRECT) {
    // NCHW transpose epilogue: [128 m][65] tile, swizzled cols, coalesced stores
    float* tb2 = (float*)lA;
    float* obase = outp + (((size_t)(b * 256)) << 12) + (m0 & 4095);
    __syncthreads();
    #pragma unroll 1
    for (int c4 = 0; c4 < 4; ++c4) {
      if (wn == c4) {
        #pragma unroll
        for (int nf = 0; nf < 4; ++nf) {
          float al = alpha[c4 * 64 + nf * 16 + li];
          #pragma unroll
          for (int mf = 0; mf < 4; ++mf) {
            int cs = (li + nf * 16) ^ ((wm * 2 + (mf >> 1)) & 3);
            #pragma unroll
            for (int r = 0; r < 4; ++r)
              tb2[(wm * 64 + mf * 16 + 4 * kq + r) * 65 + cs] =
                  facc[mf][nf][r] * al;
          }
        }
      }
      __syncthreads();
      #pragma unroll
      for (int it = 0; it < 4; ++it) {
        int flat = tid + it * 512;
        int ch = flat >> 5, mg = flat & 31;
        int chs = ch ^ ((mg >> 3) & 3);
        f32x4 v;
        #pragma unroll
        for (int e = 0; e < 4; ++e) v[e] = tb2[(mg * 4 + e) * 65 + chs];
        *(f32x4*)(obase + (((size_t)(c4 * 64 + ch)) << 12) + mg * 4) = v;
      }
      __syncthreads();
    }
  }
}

extern "C" void kernel_launch(void* const* d_in, const int* in_sizes, int n_in,
                              void* d_out, int out_size, void* d_ws, size_t ws_size,
                              hipStream_t stream) {
  const float* x      = (const float*)d_in[0];
  const float* t      = (const float*)d_in[1];
  const float* w1     = (const float*)d_in[2];
  const float* w2     = (const float*)d_in[3];
  const float* wskip  = (const float*)d_in[4];
  const float* gamma1 = (const float*)d_in[5];
  const float* beta1  = (const float*)d_in[6];
  const float* gamma2 = (const float*)d_in[7];
  const float* beta2  = (const float*)d_in[8];
  const float* tw     = (const float*)d_in[9];
  const float* tb     = (const float*)d_in[10];
  float* out = (float*)d_out;

  uint8_t* base = (uint8_t*)d_ws;
  size_t off = 0;
  auto alloc = [&](size_t bytes) {
    void* p = base + off;
    off += (bytes + 255) & ~(size_t)255;
    return p;
  };
  // 96 i8 planes of [66][66][128]: first 32 = a1p, next 64 = a2p
  u8* Abuf     = (u8*)alloc((size_t)96 * 557568);
  u8* a1p      = Abuf;
  u8* a2p      = Abuf + (size_t)32 * 557568;
  u16* xb      = (u16*)alloc((size_t)131072 * 128 * 2);
  float* h     = (float*)alloc((size_t)131072 * 256 * 4);
  u8* w1s      = (u8*)alloc((size_t)18 * 16384);
  u8* w2s      = (u8*)alloc((size_t)36 * 16384);
  u16* wskB    = (u16*)alloc((size_t)2 * 16384 * 2);
  float* temb  = (float*)alloc(32 * 256 * 4);
  float* alpha1 = (float*)alloc(256 * 4);
  float* alpha2 = (float*)alloc(256 * 4);
  float* p1    = (float*)alloc(1024 * 4);
  float* pS    = (float*)alloc((size_t)256 * 1024 * 4);
  float* pQ    = (float*)alloc((size_t)256 * 1024 * 4);
  float* sc1   = (float*)alloc(128 * 4);
  float* off1  = (float*)alloc(128 * 4);
  float* sc2   = (float*)alloc(256 * 4);
  float* off2  = (float*)alloc(256 * 4);

  border_zero<<<96, 256, 0, stream>>>(Abuf);

  bn1_stage1<<<512, 256, 0, stream>>>(x, p1);
  bn1_stage2<<<1, 128, 0, stream>>>(p1, gamma1, beta1, sc1, off1);
  prep_weights<<<256, 256, 0, stream>>>(w1, w2, wskip, w1s, w2s, wskB, alpha1, alpha2);
  temb_k<<<32, 256, 0, stream>>>(t, tw, tb, temb);
  binact1<<<2048, 256, 0, stream>>>(x, sc1, off1, a1p, xb);

  // conv1: i8, writes h + BN2 per-block partials
  convk<1, false, true, true, false><<<1024, 512, 0, stream>>>(
      a1p, xb, w1s, (const u16*)nullptr, alpha1, temb, h, pS, pQ);

  bn2_stage2b<<<256, 256, 0, stream>>>(pS, pQ, gamma2, beta2, sc2, off2);
  binact2<<<2048, 256, 0, stream>>>(h, sc2, off2, a2p);

  // conv2: i8 + bf16 skip tail, direct NCHW output
  convk<2, true, false, false, true><<<1024, 512, 0, stream>>>(
      a2p, xb, w2s, wskB, alpha2, (const float*)nullptr, out,
      (float*)nullptr, (float*)nullptr);

  (void)in_sizes; (void)n_in; (void)out_size; (void)ws_size;
}